// Round 1
// baseline (422.325 us; speedup 1.0000x reference)
//
#include <hip/hip_runtime.h>
#include <hip/hip_bf16.h>
#include <cstdint>
#include <cstddef>

#ifndef __has_builtin
#define __has_builtin(x) 0
#endif

#define DEVI __device__ __forceinline__

typedef __attribute__((ext_vector_type(8))) __bf16 bf16x8;
typedef __attribute__((ext_vector_type(4))) float float4v;
typedef __attribute__((ext_vector_type(4))) unsigned short ushort4v;

constexpr int Bd = 4, Sd = 1024, Ld = 2048, Hd = 16, Dd = 64;

DEVI unsigned short f2bf(float x){
  union { float f; unsigned u; } v; v.f = x;
  unsigned r = v.u + 0x7fffu + ((v.u >> 16) & 1u);
  return (unsigned short)(r >> 16);
}

DEVI float fast_exp2(float x){
#if __has_builtin(__builtin_amdgcn_exp2f)
  return __builtin_amdgcn_exp2f(x);
#else
  return exp2f(x);
#endif
}

DEVI void gload_lds16(const void* g, void* lds){
  __builtin_amdgcn_global_load_lds(
      (const __attribute__((address_space(1))) void*)g,
      (__attribute__((address_space(3))) void*)lds,
      16, 0, 0);
}

DEVI float4v mfma_bf16(bf16x8 a, bf16x8 b, float4v c){
  return __builtin_amdgcn_mfma_f32_16x16x32_bf16(a, b, c, 0, 0, 0);
}

// ---------------- prep kernels ----------------

__global__ void wcast_kernel(const float* __restrict__ Wk, const float* __restrict__ Wq,
                             const float* __restrict__ Wp,
                             unsigned short* __restrict__ Wkbf, unsigned short* __restrict__ Wqbf,
                             unsigned short* __restrict__ Wpbf, float ck){
  size_t i = ((size_t)blockIdx.x * 256 + threadIdx.x) * 4;
  float4v a = *(const float4v*)(Wk + i);
  float4v b = *(const float4v*)(Wq + i);
  float4v c = *(const float4v*)(Wp + i);
  ushort4v oa = { f2bf(a[0]*ck), f2bf(a[1]*ck), f2bf(a[2]*ck), f2bf(a[3]*ck) };
  ushort4v ob = { f2bf(b[0]), f2bf(b[1]), f2bf(b[2]), f2bf(b[3]) };
  ushort4v oc = { f2bf(c[0]), f2bf(c[1]), f2bf(c[2]), f2bf(c[3]) };
  *(ushort4v*)(Wkbf + i) = oa;
  *(ushort4v*)(Wqbf + i) = ob;
  *(ushort4v*)(Wpbf + i) = oc;
}

// x (B,S,L) f32 -> Xt (B,L,S) bf16
__global__ void transpose_cast(const float* __restrict__ x, unsigned short* __restrict__ Xt){
  __shared__ float tile[32][33];
  const int b = blockIdx.z;
  const int l0 = blockIdx.x * 32;
  const int s0 = blockIdx.y * 32;
  const int tx = threadIdx.x, ty = threadIdx.y;  // 32 x 8
  #pragma unroll
  for (int r = 0; r < 32; r += 8)
    tile[ty + r][tx] = x[((size_t)b*Sd + s0 + ty + r)*Ld + l0 + tx];
  __syncthreads();
  #pragma unroll
  for (int r = 0; r < 32; r += 8)
    Xt[((size_t)b*Ld + l0 + ty + r)*Sd + s0 + tx] = f2bf(tile[tx][ty + r]);
}

// Vp[b][c][l] = bf16( x[b][c][l] * invZ[(b*16 + c/64)][l] )
__global__ void vprime_kernel(const float* __restrict__ x, const float* __restrict__ invZ,
                              unsigned short* __restrict__ Vp){
  size_t idx = ((size_t)blockIdx.x * 256 + threadIdx.x) * 4;
  const int l = (int)(idx & (Ld - 1));
  const int c = (int)((idx >> 11) & (Sd - 1));
  const int b = (int)(idx >> 21);
  const int h = c >> 6;
  float4v xv = *(const float4v*)(x + idx);
  float4v zv = *(const float4v*)(invZ + ((size_t)(b*Hd + h) * Ld + l));
  ushort4v o = { f2bf(xv[0]*zv[0]), f2bf(xv[1]*zv[1]), f2bf(xv[2]*zv[2]), f2bf(xv[3]*zv[3]) };
  *(ushort4v*)(Vp + idx) = o;
}

// ---------------- conv1x1 GEMM (128x128 tile, BK=32, dbuf, global_load_lds) ----------------
// A: (Sd, Sd) bf16 row-major. Bt: (Bd, Ld, Sd) bf16 (n rows, k contiguous).
// OUT_MODE 0: outT (Bd, Ld, Sd) bf16 (transposed). OUT_MODE 1: outF (Bd, Sd, Ld) f32.
template<int OUT_MODE>
__global__ __launch_bounds__(256, 2)
void conv_gemm(const unsigned short* __restrict__ A,
               const unsigned short* __restrict__ Bt,
               const float* __restrict__ bias, float bscale,
               unsigned short* __restrict__ outT,
               float* __restrict__ outF)
{
  constexpr int BK = 32;
  constexpr int NKSTEP = Sd / BK;  // 32
  __shared__ __attribute__((aligned(16))) unsigned short Abuf[2][128*BK];
  __shared__ __attribute__((aligned(16))) unsigned short Bbuf[2][128*BK];

  const int b  = blockIdx.z;
  const int n0 = blockIdx.x * 128;
  const int m0 = blockIdx.y * 128;
  const int tid = threadIdx.x;
  const int w = tid >> 6, lane = tid & 63, lr = lane & 15, lg = lane >> 4;
  const int wm = (w >> 1) * 64, wn = (w & 1) * 64;

  const unsigned short* Abase = A + (size_t)m0 * Sd;
  const unsigned short* Bbase = Bt + ((size_t)b * Ld + n0) * Sd;

  // staging: slot = p*256+tid; row = slot>>2 (0..127), c = slot&3 (16B chunks of a 64B row)
  // source chunk swizzle: csrc = c ^ ((row>>1)&3); LDS stays linear.
  const int srow = [](int t){ return t >> 2; }( tid );  // varies with p by +64
  auto stage = [&](int bf, int kt){
    #pragma unroll
    for (int p = 0; p < 2; ++p){
      int slot = p*256 + tid;
      int row = slot >> 2, c = slot & 3;
      int csrc = c ^ ((row >> 1) & 3);
      gload_lds16(Abase + (size_t)row * Sd + kt*BK + csrc*8,
                  (void*)(&Abuf[bf][(size_t)(p*256 + w*64) * 8]));
    }
    #pragma unroll
    for (int p = 0; p < 2; ++p){
      int slot = p*256 + tid;
      int row = slot >> 2, c = slot & 3;
      int csrc = c ^ ((row >> 1) & 3);
      gload_lds16(Bbase + (size_t)row * Sd + kt*BK + csrc*8,
                  (void*)(&Bbuf[bf][(size_t)(p*256 + w*64) * 8]));
    }
  };
  (void)srow;

  const int gsw = lg ^ ((lr >> 1) & 3);  // swizzled chunk for fragment reads

  float4v acc[4][4];
  #pragma unroll
  for (int i = 0; i < 4; ++i)
    #pragma unroll
    for (int j = 0; j < 4; ++j)
      acc[i][j] = (float4v){0.f, 0.f, 0.f, 0.f};

  stage(0, 0);
  __syncthreads();
  int cur = 0;
  for (int kt = 0; kt < NKSTEP; ++kt){
    if (kt + 1 < NKSTEP) stage(cur ^ 1, kt + 1);
    bf16x8 af[4], bfv[4];
    #pragma unroll
    for (int i = 0; i < 4; ++i){
      int row = wm + i*16 + lr;
      af[i] = *(const bf16x8*)((const char*)&Abuf[cur][0] + (size_t)row*64 + gsw*16);
    }
    #pragma unroll
    for (int j = 0; j < 4; ++j){
      int row = wn + j*16 + lr;
      bfv[j] = *(const bf16x8*)((const char*)&Bbuf[cur][0] + (size_t)row*64 + gsw*16);
    }
    #pragma unroll
    for (int i = 0; i < 4; ++i)
      #pragma unroll
      for (int j = 0; j < 4; ++j)
        acc[i][j] = mfma_bf16(af[i], bfv[j], acc[i][j]);
    __syncthreads();
    cur ^= 1;
  }

  #pragma unroll
  for (int i = 0; i < 4; ++i){
    const int mb = m0 + wm + i*16 + lg*4;
    float4v bv = *(const float4v*)(bias + mb);
    #pragma unroll
    for (int j = 0; j < 4; ++j){
      const int n = n0 + wn + j*16 + lr;
      float4v v = acc[i][j];
      float o0 = v[0] + bscale*bv[0];
      float o1 = v[1] + bscale*bv[1];
      float o2 = v[2] + bscale*bv[2];
      float o3 = v[3] + bscale*bv[3];
      if (OUT_MODE == 0){
        ushort4v o = { f2bf(o0), f2bf(o1), f2bf(o2), f2bf(o3) };
        *(ushort4v*)(outT + ((size_t)b*Ld + n)*Sd + mb) = o;
      } else {
        outF[((size_t)b*Sd + mb + 0)*Ld + n] = o0;
        outF[((size_t)b*Sd + mb + 1)*Ld + n] = o1;
        outF[((size_t)b*Sd + mb + 2)*Ld + n] = o2;
        outF[((size_t)b*Sd + mb + 3)*Ld + n] = o3;
      }
    }
  }
}

// ---------------- softmax denominators: invZ[bh][i] = 1 / sum_j 2^(K'^T Q) ----------------
__global__ __launch_bounds__(256, 2)
void stats_kernel(const unsigned short* __restrict__ Kt,
                  const unsigned short* __restrict__ Qt,
                  float* __restrict__ invZ)
{
  const int bh = blockIdx.y, b = bh >> 4, h = bh & 15;
  const int i0 = blockIdx.x * 64;
  const int tid = threadIdx.x, w = tid >> 6, lane = tid & 63, lr = lane & 15, lg = lane >> 4;

  bf16x8 ka[4][2];
  #pragma unroll
  for (int is = 0; is < 4; ++is)
    #pragma unroll
    for (int ks = 0; ks < 2; ++ks)
      ka[is][ks] = *(const bf16x8*)(Kt + ((size_t)b*Ld + i0 + is*16 + lr)*Sd + h*64 + lg*8 + ks*32);

  float z[4][4] = {};
  for (int js = 0; js < 32; ++js){
    const int jw = js*64 + w*16;
    bf16x8 qb[2];
    #pragma unroll
    for (int ks = 0; ks < 2; ++ks)
      qb[ks] = *(const bf16x8*)(Qt + ((size_t)b*Ld + jw + lr)*Sd + h*64 + lg*8 + ks*32);
    #pragma unroll
    for (int is = 0; is < 4; ++is){
      float4v acc = {0.f, 0.f, 0.f, 0.f};
      acc = mfma_bf16(ka[is][0], qb[0], acc);
      acc = mfma_bf16(ka[is][1], qb[1], acc);
      #pragma unroll
      for (int r = 0; r < 4; ++r) z[is][r] += fast_exp2(acc[r]);
    }
  }
  #pragma unroll
  for (int is = 0; is < 4; ++is)
    #pragma unroll
    for (int r = 0; r < 4; ++r){
      float v = z[is][r];
      #pragma unroll
      for (int m = 1; m < 16; m <<= 1) v += __shfl_xor(v, m, 64);
      z[is][r] = v;
    }
  __shared__ float zred[4][64];
  if (lr == 0){
    #pragma unroll
    for (int is = 0; is < 4; ++is)
      #pragma unroll
      for (int r = 0; r < 4; ++r)
        zred[w][is*16 + lg*4 + r] = z[is][r];
  }
  __syncthreads();
  if (tid < 64){
    float zt = zred[0][tid] + zred[1][tid] + zred[2][tid] + zred[3][tid];
    invZ[(size_t)bh * Ld + i0 + tid] = 1.0f / zt;
  }
}

// ---------------- PV pass: AOt[b][j][c] = sum_i Vp[c][i] * 2^(s[i,j]) ----------------
__global__ __launch_bounds__(256, 2)
void attn_pv_kernel(const unsigned short* __restrict__ Kt,
                    const unsigned short* __restrict__ Qt,
                    const unsigned short* __restrict__ Vp,
                    unsigned short* __restrict__ AOt)
{
  __shared__ __attribute__((aligned(16))) unsigned short Ktile[64*64];   // 8 KB
  __shared__ __attribute__((aligned(16))) unsigned short Pt[4][16][80];  // padded pitch

  const int bh = blockIdx.y, b = bh >> 4, h = bh & 15;
  const int j0 = blockIdx.x * 64;
  const int tid = threadIdx.x, w = tid >> 6, lane = tid & 63, lr = lane & 15, lg = lane >> 4;
  const int jw = j0 + w*16;

  bf16x8 qb[2];
  #pragma unroll
  for (int ks = 0; ks < 2; ++ks)
    qb[ks] = *(const bf16x8*)(Qt + ((size_t)b*Ld + jw + lr)*Sd + h*64 + lg*8 + ks*32);

  float4v oacc[4];
  #pragma unroll
  for (int ds = 0; ds < 4; ++ds) oacc[ds] = (float4v){0.f, 0.f, 0.f, 0.f};

  for (int it = 0; it < 32; ++it){
    const int i0 = it * 64;
    __syncthreads();   // everyone done reading Ktile from previous iter
    // stage K tile (64 i-rows x 64 d); row pitch 128B (8 granules), swizzle g ^= (row&7)
    #pragma unroll
    for (int p = 0; p < 2; ++p){
      int slot = p*256 + tid;
      int row = slot >> 3, g = slot & 7;
      int gsrc = g ^ (row & 7);
      gload_lds16(Kt + ((size_t)b*Ld + i0 + row)*Sd + h*64 + gsrc*8,
                  (void*)(&Ktile[(size_t)(p*256 + w*64) * 8]));
    }
    // V fragments (global; independent, issued before the barrier wait)
    bf16x8 va[4][2];
    #pragma unroll
    for (int ds = 0; ds < 4; ++ds)
      #pragma unroll
      for (int ks = 0; ks < 2; ++ks)
        va[ds][ks] = *(const bf16x8*)(Vp + ((size_t)b*Sd + h*64 + ds*16 + lr)*Ld + i0 + lg*8 + ks*32);
    __syncthreads();   // Ktile ready (vmcnt drained)

    // S tile + exp2 -> Pt (per-wave buffer, transposed [j][i] so PV B-frags are contiguous)
    #pragma unroll
    for (int is = 0; is < 4; ++is){
      float4v sacc = {0.f, 0.f, 0.f, 0.f};
      #pragma unroll
      for (int ks = 0; ks < 2; ++ks){
        int row = is*16 + lr;
        int g = (lg + 4*ks) ^ (lr & 7);
        bf16x8 kf = *(const bf16x8*)((const char*)Ktile + (size_t)row*128 + g*16);
        sacc = mfma_bf16(kf, qb[ks], sacc);
      }
      ushort4v pv = { f2bf(fast_exp2(sacc[0])), f2bf(fast_exp2(sacc[1])),
                      f2bf(fast_exp2(sacc[2])), f2bf(fast_exp2(sacc[3])) };
      *(ushort4v*)(&Pt[w][lr][is*16 + lg*4]) = pv;
    }
    // PV MFMAs (compiler inserts lgkmcnt for the Pt write->read dependency)
    #pragma unroll
    for (int ks = 0; ks < 2; ++ks){
      bf16x8 pb = *(const bf16x8*)(&Pt[w][lr][lg*8 + ks*32]);
      #pragma unroll
      for (int ds = 0; ds < 4; ++ds)
        oacc[ds] = mfma_bf16(va[ds][ks], pb, oacc[ds]);
    }
  }

  #pragma unroll
  for (int ds = 0; ds < 4; ++ds){
    float4v v = oacc[ds];
    ushort4v o = { f2bf(v[0]), f2bf(v[1]), f2bf(v[2]), f2bf(v[3]) };
    *(ushort4v*)(AOt + ((size_t)b*Ld + jw + lr)*Sd + h*64 + ds*16 + lg*4) = o;
  }
}

// ---------------- launch ----------------

extern "C" void kernel_launch(void* const* d_in, const int* in_sizes, int n_in,
                              void* d_out, int out_size, void* d_ws, size_t ws_size,
                              hipStream_t stream)
{
  const float* x  = (const float*)d_in[0];
  const float* Wk = (const float*)d_in[1];
  const float* bk = (const float*)d_in[2];
  const float* Wq = (const float*)d_in[3];
  const float* bq = (const float*)d_in[4];
  const float* Wp = (const float*)d_in[5];
  const float* bp = (const float*)d_in[6];
  float* out = (float*)d_out;

  char* ws = (char*)d_ws;
  const size_t SZ_BLS = (size_t)Bd * Ld * Sd * 2;   // 16 MB
  unsigned short* Xt   = (unsigned short*)(ws);
  unsigned short* Kt   = (unsigned short*)(ws + SZ_BLS);
  unsigned short* Qt   = (unsigned short*)(ws + 2*SZ_BLS);
  unsigned short* AOt  = (unsigned short*)(ws + 3*SZ_BLS);
  unsigned short* Wkbf = (unsigned short*)(ws + 4*SZ_BLS);
  unsigned short* Wqbf = (unsigned short*)(ws + 4*SZ_BLS + (size_t)2097152);
  unsigned short* Wpbf = (unsigned short*)(ws + 4*SZ_BLS + (size_t)2*2097152);
  float* invZ          = (float*)(ws + 4*SZ_BLS + (size_t)3*2097152);
  unsigned short* Vp   = Xt;  // alias: Xt is dead after the Q conv

  // fold (2/L)*log2(e) into K so scores come out in log2 domain
  const float ck = (2.0f / (float)Ld) * 1.44269504088896f;

  wcast_kernel<<<1024, 256, 0, stream>>>(Wk, Wq, Wp, Wkbf, Wqbf, Wpbf, ck);
  transpose_cast<<<dim3(Ld/32, Sd/32, Bd), dim3(32, 8), 0, stream>>>(x, Xt);

  dim3 cg(Ld/128, Sd/128, Bd);
  conv_gemm<0><<<cg, 256, 0, stream>>>(Wkbf, Xt, bk, ck,   Kt, nullptr);
  conv_gemm<0><<<cg, 256, 0, stream>>>(Wqbf, Xt, bq, 1.0f, Qt, nullptr);

  stats_kernel<<<dim3(Ld/64, Bd*Hd), 256, 0, stream>>>(Kt, Qt, invZ);
  vprime_kernel<<<(Bd*(size_t)Sd*Ld/4)/256, 256, 0, stream>>>(x, invZ, Vp);
  attn_pv_kernel<<<dim3(Ld/64, Bd*Hd), 256, 0, stream>>>(Kt, Qt, Vp, AOt);

  conv_gemm<1><<<cg, 256, 0, stream>>>(Wpbf, AOt, bp, 1.0f, nullptr, out);
}

// Round 3
// 277.854 us; speedup vs baseline: 1.5200x; 1.5200x over previous
//
#include <hip/hip_runtime.h>
#include <hip/hip_bf16.h>
#include <cstdint>
#include <cstddef>

#ifndef __has_builtin
#define __has_builtin(x) 0
#endif

#define DEVI __device__ __forceinline__

typedef __attribute__((ext_vector_type(8))) __bf16 bf16x8;
typedef __attribute__((ext_vector_type(4))) float float4v;
typedef __attribute__((ext_vector_type(16))) float float16v;
typedef __attribute__((ext_vector_type(4))) unsigned short ushort4v;

constexpr int Bd = 4, Sd = 1024, Ld = 2048, Hd = 16, Dd = 64;

DEVI unsigned short f2bf(float x){
  union { float f; unsigned u; } v; v.f = x;
  unsigned r = v.u + 0x7fffu + ((v.u >> 16) & 1u);
  return (unsigned short)(r >> 16);
}

DEVI float fast_exp2(float x){
#if __has_builtin(__builtin_amdgcn_exp2f)
  return __builtin_amdgcn_exp2f(x);
#else
  return exp2f(x);
#endif
}

DEVI void gload_lds16(const void* g, void* lds){
  __builtin_amdgcn_global_load_lds(
      (const __attribute__((address_space(1))) void*)g,
      (__attribute__((address_space(3))) void*)lds,
      16, 0, 0);
}

DEVI float4v mfma_bf16(bf16x8 a, bf16x8 b, float4v c){
  return __builtin_amdgcn_mfma_f32_16x16x32_bf16(a, b, c, 0, 0, 0);
}

DEVI float16v mfma32_bf16(bf16x8 a, bf16x8 b, float16v c){
  return __builtin_amdgcn_mfma_f32_32x32x16_bf16(a, b, c, 0, 0, 0);
}

// ---------------- prep kernels ----------------

__global__ void wcast_kernel(const float* __restrict__ Wk, const float* __restrict__ Wq,
                             const float* __restrict__ Wp,
                             unsigned short* __restrict__ Wkbf, unsigned short* __restrict__ Wqbf,
                             unsigned short* __restrict__ Wpbf, float ck){
  size_t i = ((size_t)blockIdx.x * 256 + threadIdx.x) * 4;
  float4v a = *(const float4v*)(Wk + i);
  float4v b = *(const float4v*)(Wq + i);
  float4v c = *(const float4v*)(Wp + i);
  ushort4v oa = { f2bf(a[0]*ck), f2bf(a[1]*ck), f2bf(a[2]*ck), f2bf(a[3]*ck) };
  ushort4v ob = { f2bf(b[0]), f2bf(b[1]), f2bf(b[2]), f2bf(b[3]) };
  ushort4v oc = { f2bf(c[0]), f2bf(c[1]), f2bf(c[2]), f2bf(c[3]) };
  *(ushort4v*)(Wkbf + i) = oa;
  *(ushort4v*)(Wqbf + i) = ob;
  *(ushort4v*)(Wpbf + i) = oc;
}

// x (B,S,L) f32 -> Xt (B,L,S) bf16
__global__ void transpose_cast(const float* __restrict__ x, unsigned short* __restrict__ Xt){
  __shared__ float tile[32][33];
  const int b = blockIdx.z;
  const int l0 = blockIdx.x * 32;
  const int s0 = blockIdx.y * 32;
  const int tx = threadIdx.x, ty = threadIdx.y;  // 32 x 8
  #pragma unroll
  for (int r = 0; r < 32; r += 8)
    tile[ty + r][tx] = x[((size_t)b*Sd + s0 + ty + r)*Ld + l0 + tx];
  __syncthreads();
  #pragma unroll
  for (int r = 0; r < 32; r += 8)
    Xt[((size_t)b*Ld + l0 + ty + r)*Sd + s0 + tx] = f2bf(tile[tx][ty + r]);
}

// Vp[b][c][l] = bf16( x[b][c][l] * invZ[(b*16 + c/64)][l] )
__global__ void vprime_kernel(const float* __restrict__ x, const float* __restrict__ invZ,
                              unsigned short* __restrict__ Vp){
  size_t idx = ((size_t)blockIdx.x * 256 + threadIdx.x) * 4;
  const int l = (int)(idx & (Ld - 1));
  const int c = (int)((idx >> 11) & (Sd - 1));
  const int b = (int)(idx >> 21);
  const int h = c >> 6;
  float4v xv = *(const float4v*)(x + idx);
  float4v zv = *(const float4v*)(invZ + ((size_t)(b*Hd + h) * Ld + l));
  ushort4v o = { f2bf(xv[0]*zv[0]), f2bf(xv[1]*zv[1]), f2bf(xv[2]*zv[2]), f2bf(xv[3]*zv[3]) };
  *(ushort4v*)(Vp + idx) = o;
}

// ---------------- conv1x1 GEMM (128x128 tile, BK=32, dbuf, global_load_lds) ----------------
template<int OUT_MODE>
__global__ __launch_bounds__(256, 2)
void conv_gemm(const unsigned short* __restrict__ A,
               const unsigned short* __restrict__ Bt,
               const float* __restrict__ bias, float bscale,
               unsigned short* __restrict__ outT,
               float* __restrict__ outF)
{
  constexpr int BK = 32;
  constexpr int NKSTEP = Sd / BK;  // 32
  __shared__ __attribute__((aligned(16))) unsigned short Abuf[2][128*BK];
  __shared__ __attribute__((aligned(16))) unsigned short Bbuf[2][128*BK];

  const int b  = blockIdx.z;
  const int n0 = blockIdx.x * 128;
  const int m0 = blockIdx.y * 128;
  const int tid = threadIdx.x;
  const int w = tid >> 6, lane = tid & 63, lr = lane & 15, lg = lane >> 4;
  const int wm = (w >> 1) * 64, wn = (w & 1) * 64;

  const unsigned short* Abase = A + (size_t)m0 * Sd;
  const unsigned short* Bbase = Bt + ((size_t)b * Ld + n0) * Sd;

  auto stage = [&](int bf, int kt){
    #pragma unroll
    for (int p = 0; p < 2; ++p){
      int slot = p*256 + tid;
      int row = slot >> 2, c = slot & 3;
      int csrc = c ^ ((row >> 1) & 3);
      gload_lds16(Abase + (size_t)row * Sd + kt*BK + csrc*8,
                  (void*)(&Abuf[bf][(size_t)(p*256 + w*64) * 8]));
    }
    #pragma unroll
    for (int p = 0; p < 2; ++p){
      int slot = p*256 + tid;
      int row = slot >> 2, c = slot & 3;
      int csrc = c ^ ((row >> 1) & 3);
      gload_lds16(Bbase + (size_t)row * Sd + kt*BK + csrc*8,
                  (void*)(&Bbuf[bf][(size_t)(p*256 + w*64) * 8]));
    }
  };

  const int gsw = lg ^ ((lr >> 1) & 3);

  float4v acc[4][4];
  #pragma unroll
  for (int i = 0; i < 4; ++i)
    #pragma unroll
    for (int j = 0; j < 4; ++j)
      acc[i][j] = (float4v){0.f, 0.f, 0.f, 0.f};

  stage(0, 0);
  __syncthreads();
  int cur = 0;
  for (int kt = 0; kt < NKSTEP; ++kt){
    if (kt + 1 < NKSTEP) stage(cur ^ 1, kt + 1);
    bf16x8 af[4], bfv[4];
    #pragma unroll
    for (int i = 0; i < 4; ++i){
      int row = wm + i*16 + lr;
      af[i] = *(const bf16x8*)((const char*)&Abuf[cur][0] + (size_t)row*64 + gsw*16);
    }
    #pragma unroll
    for (int j = 0; j < 4; ++j){
      int row = wn + j*16 + lr;
      bfv[j] = *(const bf16x8*)((const char*)&Bbuf[cur][0] + (size_t)row*64 + gsw*16);
    }
    #pragma unroll
    for (int i = 0; i < 4; ++i)
      #pragma unroll
      for (int j = 0; j < 4; ++j)
        acc[i][j] = mfma_bf16(af[i], bfv[j], acc[i][j]);
    __syncthreads();
    cur ^= 1;
  }

  #pragma unroll
  for (int i = 0; i < 4; ++i){
    const int mb = m0 + wm + i*16 + lg*4;
    float4v bv = *(const float4v*)(bias + mb);
    #pragma unroll
    for (int j = 0; j < 4; ++j){
      const int n = n0 + wn + j*16 + lr;
      float4v v = acc[i][j];
      float o0 = v[0] + bscale*bv[0];
      float o1 = v[1] + bscale*bv[1];
      float o2 = v[2] + bscale*bv[2];
      float o3 = v[3] + bscale*bv[3];
      if (OUT_MODE == 0){
        ushort4v o = { f2bf(o0), f2bf(o1), f2bf(o2), f2bf(o3) };
        *(ushort4v*)(outT + ((size_t)b*Ld + n)*Sd + mb) = o;
      } else {
        outF[((size_t)b*Sd + mb + 0)*Ld + n] = o0;
        outF[((size_t)b*Sd + mb + 1)*Ld + n] = o1;
        outF[((size_t)b*Sd + mb + 2)*Ld + n] = o2;
        outF[((size_t)b*Sd + mb + 3)*Ld + n] = o3;
      }
    }
  }
}

// ---------------- softmax denominators: invZ[bh][i] = 1 / sum_j 2^(K'^T Q) ----------------
__global__ __launch_bounds__(256, 2)
void stats_kernel(const unsigned short* __restrict__ Kt,
                  const unsigned short* __restrict__ Qt,
                  float* __restrict__ invZ)
{
  const int bh = blockIdx.y, b = bh >> 4, h = bh & 15;
  const int i0 = blockIdx.x * 64;
  const int tid = threadIdx.x, w = tid >> 6, lane = tid & 63, lr = lane & 15, lg = lane >> 4;

  bf16x8 ka[4][2];
  #pragma unroll
  for (int is = 0; is < 4; ++is)
    #pragma unroll
    for (int ks = 0; ks < 2; ++ks)
      ka[is][ks] = *(const bf16x8*)(Kt + ((size_t)b*Ld + i0 + is*16 + lr)*Sd + h*64 + lg*8 + ks*32);

  float z[4][4] = {};
  for (int js = 0; js < 32; ++js){
    const int jw = js*64 + w*16;
    bf16x8 qb[2];
    #pragma unroll
    for (int ks = 0; ks < 2; ++ks)
      qb[ks] = *(const bf16x8*)(Qt + ((size_t)b*Ld + jw + lr)*Sd + h*64 + lg*8 + ks*32);
    #pragma unroll
    for (int is = 0; is < 4; ++is){
      float4v acc = {0.f, 0.f, 0.f, 0.f};
      acc = mfma_bf16(ka[is][0], qb[0], acc);
      acc = mfma_bf16(ka[is][1], qb[1], acc);
      #pragma unroll
      for (int r = 0; r < 4; ++r) z[is][r] += fast_exp2(acc[r]);
    }
  }
  #pragma unroll
  for (int is = 0; is < 4; ++is)
    #pragma unroll
    for (int r = 0; r < 4; ++r){
      float v = z[is][r];
      #pragma unroll
      for (int m = 1; m < 16; m <<= 1) v += __shfl_xor(v, m, 64);
      z[is][r] = v;
    }
  __shared__ float zred[4][64];
  if (lr == 0){
    #pragma unroll
    for (int is = 0; is < 4; ++is)
      #pragma unroll
      for (int r = 0; r < 4; ++r)
        zred[w][is*16 + lg*4 + r] = z[is][r];
  }
  __syncthreads();
  if (tid < 64){
    float zt = zred[0][tid] + zred[1][tid] + zred[2][tid] + zred[3][tid];
    invZ[(size_t)bh * Ld + i0 + tid] = 1.0f / zt;
  }
}

// ---------------- PV pass v3: 32x32 MFMA, LDS-P (round-1-proven path), 2-phase prefetch ----
// AOt[b][j][c] = sum_i Vp[c][i] * 2^(s[i,j])
__global__ __launch_bounds__(256, 2)
void attn_pv_kernel(const unsigned short* __restrict__ Kt,
                    const unsigned short* __restrict__ Qt,
                    const unsigned short* __restrict__ Vp,
                    unsigned short* __restrict__ AOt)
{
  __shared__ __attribute__((aligned(16))) unsigned short Kbuf[2][64*64];  // 16 KB
  __shared__ __attribute__((aligned(16))) unsigned short Vbuf[2][64*64];  // 16 KB
  __shared__ __attribute__((aligned(16))) unsigned short Pt[4][32][72];   // 18 KB, pitch 144B

  const int bh = blockIdx.y, b = bh >> 4, h = bh & 15;
  const int j0 = blockIdx.x * 128;
  const int tid = threadIdx.x, w = tid >> 6, lane = tid & 63;
  const int l31 = lane & 31, lh = lane >> 5;
  const int jw = j0 + w * 32;

  // Q fragments (loop-invariant): B-operand, col j = jw+l31, k-elems d = ks*16+lh*8..+8
  bf16x8 qb[4];
  #pragma unroll
  for (int ks = 0; ks < 4; ++ks)
    qb[ks] = *(const bf16x8*)(Qt + ((size_t)b*Ld + jw + l31)*Sd + h*64 + ks*16 + lh*8);

  float16v oacc[2];
  #pragma unroll
  for (int ds = 0; ds < 2; ++ds)
    #pragma unroll
    for (int r = 0; r < 16; ++r) oacc[ds][r] = 0.f;

  const size_t kbase = (size_t)b*Ld*Sd + (size_t)h*64;
  const size_t vbase = ((size_t)b*Sd + h*64)*Ld;

  // stage: K tile (64 i-rows x 64 d) and V tile (64 d-rows x 64 i), 8 KB each.
  // LDS linear (granule slot = row*8+g); source granule XOR-swizzled: gsrc = g ^ (row&7).
  auto stage = [&](int bf, int it){
    const int i0 = it * 64;
    #pragma unroll
    for (int p = 0; p < 2; ++p){
      const int slot = p*256 + tid;
      const int row = slot >> 3;
      const int gsrc = (slot & 7) ^ (row & 7);
      gload_lds16(Kt + kbase + (size_t)(i0 + row)*Sd + gsrc*8,
                  (void*)(&Kbuf[bf][(size_t)slot * 8]));
      gload_lds16(Vp + vbase + (size_t)row*Ld + i0 + gsrc*8,
                  (void*)(&Vbuf[bf][(size_t)slot * 8]));
    }
  };

  stage(0, 0);
  __syncthreads();
  int cur = 0;
  for (int it = 0; it < 32; ++it){
    if (it + 1 < 32) stage(cur ^ 1, it + 1);   // prefetch overlaps compute below

    // ---- QK^T: S[i 0..63][j wave32] in two 32x32 accs (lane holds col j = l31)
    float16v sacc[2];
    #pragma unroll
    for (int is = 0; is < 2; ++is){
      #pragma unroll
      for (int r = 0; r < 16; ++r) sacc[is][r] = 0.f;
      #pragma unroll
      for (int ks = 0; ks < 4; ++ks){
        const int row = is*32 + l31;
        const int g = (2*ks + lh) ^ (l31 & 7);
        bf16x8 kf = *(const bf16x8*)((const char*)&Kbuf[cur][0] + (size_t)row*128 + g*16);
        sacc[is] = mfma32_bf16(kf, qb[ks], sacc[is]);
      }
    }

    // ---- exp2 + store P to per-wave LDS, transposed [j][i]
    // sacc[is] reg r holds S[i = is*32 + (r&3) + 8*(r>>2) + 4*lh][j = jw + l31];
    // regs 4rq..4rq+3 are 4 consecutive i -> one 8B ushort4 store.
    #pragma unroll
    for (int is = 0; is < 2; ++is){
      #pragma unroll
      for (int rq = 0; rq < 4; ++rq){
        ushort4v pv = { f2bf(fast_exp2(sacc[is][4*rq+0])),
                        f2bf(fast_exp2(sacc[is][4*rq+1])),
                        f2bf(fast_exp2(sacc[is][4*rq+2])),
                        f2bf(fast_exp2(sacc[is][4*rq+3])) };
        *(ushort4v*)(&Pt[w][l31][is*32 + 8*rq + 4*lh]) = pv;
      }
    }

    // ---- PV: out[d 0..63][j] += V (A) x P (B); B-frag k = i = kp*16 + lh*8 + t
    #pragma unroll
    for (int kp = 0; kp < 4; ++kp){
      bf16x8 pb = *(const bf16x8*)(&Pt[w][l31][kp*16 + lh*8]);
      #pragma unroll
      for (int ds = 0; ds < 2; ++ds){
        const int row = ds*32 + l31;
        const int g = (2*kp + lh) ^ (l31 & 7);
        bf16x8 vf = *(const bf16x8*)((const char*)&Vbuf[cur][0] + (size_t)row*128 + g*16);
        oacc[ds] = mfma32_bf16(vf, pb, oacc[ds]);
      }
    }

    __syncthreads();   // vmcnt(0): prefetched tile t+1 landed; barrier for dbuf WAR
    cur ^= 1;
  }

  // epilogue: oacc[ds] reg r -> d = ds*32 + (r&3) + 8*(r>>2) + 4*lh, j = jw + l31
  #pragma unroll
  for (int ds = 0; ds < 2; ++ds){
    #pragma unroll
    for (int rq = 0; rq < 4; ++rq){
      const int d0 = ds*32 + 8*rq + 4*lh;
      ushort4v o = { f2bf(oacc[ds][4*rq+0]), f2bf(oacc[ds][4*rq+1]),
                     f2bf(oacc[ds][4*rq+2]), f2bf(oacc[ds][4*rq+3]) };
      *(ushort4v*)(AOt + ((size_t)b*Ld + jw + l31)*Sd + h*64 + d0) = o;
    }
  }
}

// ---------------- launch ----------------

extern "C" void kernel_launch(void* const* d_in, const int* in_sizes, int n_in,
                              void* d_out, int out_size, void* d_ws, size_t ws_size,
                              hipStream_t stream)
{
  const float* x  = (const float*)d_in[0];
  const float* Wk = (const float*)d_in[1];
  const float* bk = (const float*)d_in[2];
  const float* Wq = (const float*)d_in[3];
  const float* bq = (const float*)d_in[4];
  const float* Wp = (const float*)d_in[5];
  const float* bp = (const float*)d_in[6];
  float* out = (float*)d_out;

  char* ws = (char*)d_ws;
  const size_t SZ_BLS = (size_t)Bd * Ld * Sd * 2;   // 16 MB
  unsigned short* Xt   = (unsigned short*)(ws);
  unsigned short* Kt   = (unsigned short*)(ws + SZ_BLS);
  unsigned short* Qt   = (unsigned short*)(ws + 2*SZ_BLS);
  unsigned short* AOt  = (unsigned short*)(ws + 3*SZ_BLS);
  unsigned short* Wkbf = (unsigned short*)(ws + 4*SZ_BLS);
  unsigned short* Wqbf = (unsigned short*)(ws + 4*SZ_BLS + (size_t)2097152);
  unsigned short* Wpbf = (unsigned short*)(ws + 4*SZ_BLS + (size_t)2*2097152);
  float* invZ          = (float*)(ws + 4*SZ_BLS + (size_t)3*2097152);
  unsigned short* Vp   = Xt;  // alias: Xt is dead after the Q conv

  const float ck = (2.0f / (float)Ld) * 1.44269504088896f;

  wcast_kernel<<<1024, 256, 0, stream>>>(Wk, Wq, Wp, Wkbf, Wqbf, Wpbf, ck);
  transpose_cast<<<dim3(Ld/32, Sd/32, Bd), dim3(32, 8), 0, stream>>>(x, Xt);

  dim3 cg(Ld/128, Sd/128, Bd);
  conv_gemm<0><<<cg, 256, 0, stream>>>(Wkbf, Xt, bk, ck,   Kt, nullptr);
  conv_gemm<0><<<cg, 256, 0, stream>>>(Wqbf, Xt, bq, 1.0f, Qt, nullptr);

  stats_kernel<<<dim3(Ld/64, Bd*Hd), 256, 0, stream>>>(Kt, Qt, invZ);
  vprime_kernel<<<(Bd*(size_t)Sd*Ld/4)/256, 256, 0, stream>>>(x, invZ, Vp);
  attn_pv_kernel<<<dim3(Ld/128, Bd*Hd), 256, 0, stream>>>(Kt, Qt, Vp, AOt);

  conv_gemm<1><<<cg, 256, 0, stream>>>(Wpbf, AOt, bp, 1.0f, nullptr, out);
}

// Round 4
// 257.841 us; speedup vs baseline: 1.6379x; 1.0776x over previous
//
#include <hip/hip_runtime.h>
#include <hip/hip_bf16.h>
#include <cstdint>
#include <cstddef>

#ifndef __has_builtin
#define __has_builtin(x) 0
#endif

#define DEVI __device__ __forceinline__

typedef __attribute__((ext_vector_type(8))) __bf16 bf16x8;
typedef __attribute__((ext_vector_type(4))) float float4v;
typedef __attribute__((ext_vector_type(16))) float float16v;
typedef __attribute__((ext_vector_type(4))) unsigned short ushort4v;
typedef __attribute__((ext_vector_type(4))) unsigned int uint4v;

constexpr int Bd = 4, Sd = 1024, Ld = 2048, Hd = 16, Dd = 64;

DEVI unsigned short f2bf(float x){
  union { float f; unsigned u; } v; v.f = x;
  unsigned r = v.u + 0x7fffu + ((v.u >> 16) & 1u);
  return (unsigned short)(r >> 16);
}

// RNE-pack two f32 -> one u32 of 2 bf16 (lo|hi<<16). Same values as f2bf pair.
DEVI unsigned pack2(float lo, float hi){
  return (unsigned)f2bf(lo) | ((unsigned)f2bf(hi) << 16);
}

DEVI float fast_exp2(float x){
#if __has_builtin(__builtin_amdgcn_exp2f)
  return __builtin_amdgcn_exp2f(x);
#else
  return exp2f(x);
#endif
}

// v_permlane32_swap_b32 D,S: D.hi <-> S.lo. new_D=[D.lo|S.lo], new_S=[D.hi|S.hi].
DEVI void plane32_swap(unsigned &a, unsigned &b){
  asm("v_permlane32_swap_b32 %0, %1" : "+v"(a), "+v"(b));
}

DEVI void gload_lds16(const void* g, void* lds){
  __builtin_amdgcn_global_load_lds(
      (const __attribute__((address_space(1))) void*)g,
      (__attribute__((address_space(3))) void*)lds,
      16, 0, 0);
}

DEVI float4v mfma_bf16(bf16x8 a, bf16x8 b, float4v c){
  return __builtin_amdgcn_mfma_f32_16x16x32_bf16(a, b, c, 0, 0, 0);
}

DEVI float16v mfma32_bf16(bf16x8 a, bf16x8 b, float16v c){
  return __builtin_amdgcn_mfma_f32_32x32x16_bf16(a, b, c, 0, 0, 0);
}

// ---------------- prep kernels ----------------

__global__ void wcast_kernel(const float* __restrict__ Wk, const float* __restrict__ Wq,
                             const float* __restrict__ Wp,
                             unsigned short* __restrict__ Wkbf, unsigned short* __restrict__ Wqbf,
                             unsigned short* __restrict__ Wpbf, float ck){
  size_t i = ((size_t)blockIdx.x * 256 + threadIdx.x) * 4;
  float4v a = *(const float4v*)(Wk + i);
  float4v b = *(const float4v*)(Wq + i);
  float4v c = *(const float4v*)(Wp + i);
  ushort4v oa = { f2bf(a[0]*ck), f2bf(a[1]*ck), f2bf(a[2]*ck), f2bf(a[3]*ck) };
  ushort4v ob = { f2bf(b[0]), f2bf(b[1]), f2bf(b[2]), f2bf(b[3]) };
  ushort4v oc = { f2bf(c[0]), f2bf(c[1]), f2bf(c[2]), f2bf(c[3]) };
  *(ushort4v*)(Wkbf + i) = oa;
  *(ushort4v*)(Wqbf + i) = ob;
  *(ushort4v*)(Wpbf + i) = oc;
}

// x (B,S,L) f32 -> Xt (B,L,S) bf16
__global__ void transpose_cast(const float* __restrict__ x, unsigned short* __restrict__ Xt){
  __shared__ float tile[32][33];
  const int b = blockIdx.z;
  const int l0 = blockIdx.x * 32;
  const int s0 = blockIdx.y * 32;
  const int tx = threadIdx.x, ty = threadIdx.y;  // 32 x 8
  #pragma unroll
  for (int r = 0; r < 32; r += 8)
    tile[ty + r][tx] = x[((size_t)b*Sd + s0 + ty + r)*Ld + l0 + tx];
  __syncthreads();
  #pragma unroll
  for (int r = 0; r < 32; r += 8)
    Xt[((size_t)b*Ld + l0 + ty + r)*Sd + s0 + tx] = f2bf(tile[tx][ty + r]);
}

// Vp[b][c][l] = bf16( x[b][c][l] * invZ[(b*16 + c/64)][l] )
__global__ void vprime_kernel(const float* __restrict__ x, const float* __restrict__ invZ,
                              unsigned short* __restrict__ Vp){
  size_t idx = ((size_t)blockIdx.x * 256 + threadIdx.x) * 4;
  const int l = (int)(idx & (Ld - 1));
  const int c = (int)((idx >> 11) & (Sd - 1));
  const int b = (int)(idx >> 21);
  const int h = c >> 6;
  float4v xv = *(const float4v*)(x + idx);
  float4v zv = *(const float4v*)(invZ + ((size_t)(b*Hd + h) * Ld + l));
  ushort4v o = { f2bf(xv[0]*zv[0]), f2bf(xv[1]*zv[1]), f2bf(xv[2]*zv[2]), f2bf(xv[3]*zv[3]) };
  *(ushort4v*)(Vp + idx) = o;
}

// ---------------- conv1x1 GEMM (128x128 tile, BK=32, dbuf, global_load_lds) ----------------
template<int OUT_MODE>
__global__ __launch_bounds__(256, 2)
void conv_gemm(const unsigned short* __restrict__ A,
               const unsigned short* __restrict__ Bt,
               const float* __restrict__ bias, float bscale,
               unsigned short* __restrict__ outT,
               float* __restrict__ outF)
{
  constexpr int BK = 32;
  constexpr int NKSTEP = Sd / BK;  // 32
  __shared__ __attribute__((aligned(16))) unsigned short Abuf[2][128*BK];
  __shared__ __attribute__((aligned(16))) unsigned short Bbuf[2][128*BK];

  const int b  = blockIdx.z;
  const int n0 = blockIdx.x * 128;
  const int m0 = blockIdx.y * 128;
  const int tid = threadIdx.x;
  const int w = tid >> 6, lane = tid & 63, lr = lane & 15, lg = lane >> 4;
  const int wm = (w >> 1) * 64, wn = (w & 1) * 64;

  const unsigned short* Abase = A + (size_t)m0 * Sd;
  const unsigned short* Bbase = Bt + ((size_t)b * Ld + n0) * Sd;

  auto stage = [&](int bf, int kt){
    #pragma unroll
    for (int p = 0; p < 2; ++p){
      int slot = p*256 + tid;
      int row = slot >> 2, c = slot & 3;
      int csrc = c ^ ((row >> 1) & 3);
      gload_lds16(Abase + (size_t)row * Sd + kt*BK + csrc*8,
                  (void*)(&Abuf[bf][(size_t)(p*256 + w*64) * 8]));
    }
    #pragma unroll
    for (int p = 0; p < 2; ++p){
      int slot = p*256 + tid;
      int row = slot >> 2, c = slot & 3;
      int csrc = c ^ ((row >> 1) & 3);
      gload_lds16(Bbase + (size_t)row * Sd + kt*BK + csrc*8,
                  (void*)(&Bbuf[bf][(size_t)(p*256 + w*64) * 8]));
    }
  };

  const int gsw = lg ^ ((lr >> 1) & 3);

  float4v acc[4][4];
  #pragma unroll
  for (int i = 0; i < 4; ++i)
    #pragma unroll
    for (int j = 0; j < 4; ++j)
      acc[i][j] = (float4v){0.f, 0.f, 0.f, 0.f};

  stage(0, 0);
  __syncthreads();
  int cur = 0;
  for (int kt = 0; kt < NKSTEP; ++kt){
    if (kt + 1 < NKSTEP) stage(cur ^ 1, kt + 1);
    bf16x8 af[4], bfv[4];
    #pragma unroll
    for (int i = 0; i < 4; ++i){
      int row = wm + i*16 + lr;
      af[i] = *(const bf16x8*)((const char*)&Abuf[cur][0] + (size_t)row*64 + gsw*16);
    }
    #pragma unroll
    for (int j = 0; j < 4; ++j){
      int row = wn + j*16 + lr;
      bfv[j] = *(const bf16x8*)((const char*)&Bbuf[cur][0] + (size_t)row*64 + gsw*16);
    }
    #pragma unroll
    for (int i = 0; i < 4; ++i)
      #pragma unroll
      for (int j = 0; j < 4; ++j)
        acc[i][j] = mfma_bf16(af[i], bfv[j], acc[i][j]);
    __syncthreads();
    cur ^= 1;
  }

  #pragma unroll
  for (int i = 0; i < 4; ++i){
    const int mb = m0 + wm + i*16 + lg*4;
    float4v bv = *(const float4v*)(bias + mb);
    #pragma unroll
    for (int j = 0; j < 4; ++j){
      const int n = n0 + wn + j*16 + lr;
      float4v v = acc[i][j];
      float o0 = v[0] + bscale*bv[0];
      float o1 = v[1] + bscale*bv[1];
      float o2 = v[2] + bscale*bv[2];
      float o3 = v[3] + bscale*bv[3];
      if (OUT_MODE == 0){
        ushort4v o = { f2bf(o0), f2bf(o1), f2bf(o2), f2bf(o3) };
        *(ushort4v*)(outT + ((size_t)b*Ld + n)*Sd + mb) = o;
      } else {
        outF[((size_t)b*Sd + mb + 0)*Ld + n] = o0;
        outF[((size_t)b*Sd + mb + 1)*Ld + n] = o1;
        outF[((size_t)b*Sd + mb + 2)*Ld + n] = o2;
        outF[((size_t)b*Sd + mb + 3)*Ld + n] = o3;
      }
    }
  }
}

// ---------------- softmax denominators: invZ[bh][i] = 1 / sum_j 2^(K'^T Q) ----------------
__global__ __launch_bounds__(256, 2)
void stats_kernel(const unsigned short* __restrict__ Kt,
                  const unsigned short* __restrict__ Qt,
                  float* __restrict__ invZ)
{
  const int bh = blockIdx.y, b = bh >> 4, h = bh & 15;
  const int i0 = blockIdx.x * 64;
  const int tid = threadIdx.x, w = tid >> 6, lane = tid & 63, lr = lane & 15, lg = lane >> 4;

  bf16x8 ka[4][2];
  #pragma unroll
  for (int is = 0; is < 4; ++is)
    #pragma unroll
    for (int ks = 0; ks < 2; ++ks)
      ka[is][ks] = *(const bf16x8*)(Kt + ((size_t)b*Ld + i0 + is*16 + lr)*Sd + h*64 + lg*8 + ks*32);

  float z[4][4] = {};
  for (int js = 0; js < 32; ++js){
    const int jw = js*64 + w*16;
    bf16x8 qb[2];
    #pragma unroll
    for (int ks = 0; ks < 2; ++ks)
      qb[ks] = *(const bf16x8*)(Qt + ((size_t)b*Ld + jw + lr)*Sd + h*64 + lg*8 + ks*32);
    #pragma unroll
    for (int is = 0; is < 4; ++is){
      float4v acc = {0.f, 0.f, 0.f, 0.f};
      acc = mfma_bf16(ka[is][0], qb[0], acc);
      acc = mfma_bf16(ka[is][1], qb[1], acc);
      #pragma unroll
      for (int r = 0; r < 4; ++r) z[is][r] += fast_exp2(acc[r]);
    }
  }
  #pragma unroll
  for (int is = 0; is < 4; ++is)
    #pragma unroll
    for (int r = 0; r < 4; ++r){
      float v = z[is][r];
      #pragma unroll
      for (int m = 1; m < 16; m <<= 1) v += __shfl_xor(v, m, 64);
      z[is][r] = v;
    }
  __shared__ float zred[4][64];
  if (lr == 0){
    #pragma unroll
    for (int is = 0; is < 4; ++is)
      #pragma unroll
      for (int r = 0; r < 4; ++r)
        zred[w][is*16 + lg*4 + r] = z[is][r];
  }
  __syncthreads();
  if (tid < 64){
    float zt = zred[0][tid] + zred[1][tid] + zred[2][tid] + zred[3][tid];
    invZ[(size_t)bh * Ld + i0 + tid] = 1.0f / zt;
  }
}

// ---------------- PV pass v4: 32x32 MFMA, in-register P (RNE pack + permlane), dbuf ----
// AOt[b][j][c] = sum_i Vp[c][i] * 2^(s[i,j])
__global__ __launch_bounds__(256, 4)
void attn_pv_kernel(const unsigned short* __restrict__ Kt,
                    const unsigned short* __restrict__ Qt,
                    const unsigned short* __restrict__ Vp,
                    unsigned short* __restrict__ AOt)
{
  __shared__ __attribute__((aligned(16))) unsigned short Kbuf[2][64*64];  // 16 KB
  __shared__ __attribute__((aligned(16))) unsigned short Vbuf[2][64*64];  // 16 KB

  // XCD-aware remap: all 16 j-blocks of one bh on one XCD (K/V L2 reuse).
  const int m = blockIdx.x;
  const int xcd = m & 7, slot = m >> 3;        // 8 XCDs, 128 slots each
  const int bh = xcd * 8 + (slot >> 4);        // 8 bh per XCD
  const int jb = slot & 15;
  const int b = bh >> 4, h = bh & 15;
  const int j0 = jb * 128;

  const int tid = threadIdx.x, w = tid >> 6, lane = tid & 63;
  const int l31 = lane & 31, lh = lane >> 5;
  const int jw = j0 + w * 32;

  // Q fragments (loop-invariant): B-operand, col j = jw+l31, k-elems d = ks*16+lh*8..+8
  bf16x8 qb[4];
  #pragma unroll
  for (int ks = 0; ks < 4; ++ks)
    qb[ks] = *(const bf16x8*)(Qt + ((size_t)b*Ld + jw + l31)*Sd + h*64 + ks*16 + lh*8);

  float16v oacc[2];
  #pragma unroll
  for (int ds = 0; ds < 2; ++ds)
    #pragma unroll
    for (int r = 0; r < 16; ++r) oacc[ds][r] = 0.f;

  const size_t kbase = (size_t)b*Ld*Sd + (size_t)h*64;
  const size_t vbase = ((size_t)b*Sd + h*64)*Ld;

  // stage: K tile (64 i-rows x 64 d) and V tile (64 d-rows x 64 i), 8 KB each.
  // LDS linear (granule slot = row*8+g); source granule XOR-swizzled: gsrc = g ^ (row&7).
  auto stage = [&](int bf, int it){
    const int i0 = it * 64;
    #pragma unroll
    for (int p = 0; p < 2; ++p){
      const int slot2 = p*256 + tid;
      const int row = slot2 >> 3;
      const int gsrc = (slot2 & 7) ^ (row & 7);
      gload_lds16(Kt + kbase + (size_t)(i0 + row)*Sd + gsrc*8,
                  (void*)(&Kbuf[bf][(size_t)slot2 * 8]));
      gload_lds16(Vp + vbase + (size_t)row*Ld + i0 + gsrc*8,
                  (void*)(&Vbuf[bf][(size_t)slot2 * 8]));
    }
  };

  stage(0, 0);
  __syncthreads();
  int cur = 0;
  for (int it = 0; it < 32; ++it){
    if (it + 1 < 32) stage(cur ^ 1, it + 1);   // prefetch overlaps compute below

    // ---- QK^T: S[i 0..63][j wave32] in two 32x32 accs (lane holds col j = l31)
    float16v sacc[2];
    #pragma unroll
    for (int is = 0; is < 2; ++is){
      #pragma unroll
      for (int r = 0; r < 16; ++r) sacc[is][r] = 0.f;
      #pragma unroll
      for (int ks = 0; ks < 4; ++ks){
        const int row = is*32 + l31;
        const int g = (2*ks + lh) ^ (l31 & 7);
        bf16x8 kf = *(const bf16x8*)((const char*)&Kbuf[cur][0] + (size_t)row*128 + g*16);
        sacc[is] = mfma32_bf16(kf, qb[ks], sacc[is]);
      }
    }

    // ---- exp2 + RNE pack + permlane32_swap -> in-register PV B-frags.
    // sacc[is] reg r holds S[i = is*32 + (r&3) + 8*(r>>2) + 4*lh][j = jw + l31].
    // After pack W0..W3 (pairs of consecutive i) and swap(W0,W2), swap(W1,W3):
    // lane (l31,lh) holds P[i = base + 8*lh + t][j], t=0..7 ascending = B-frag.
    bf16x8 pf[4];
    #pragma unroll
    for (int is = 0; is < 2; ++is){
      #pragma unroll
      for (int hs = 0; hs < 2; ++hs){
        const int r0 = 8*hs;
        unsigned W0 = pack2(fast_exp2(sacc[is][r0+0]), fast_exp2(sacc[is][r0+1]));
        unsigned W1 = pack2(fast_exp2(sacc[is][r0+2]), fast_exp2(sacc[is][r0+3]));
        unsigned W2 = pack2(fast_exp2(sacc[is][r0+4]), fast_exp2(sacc[is][r0+5]));
        unsigned W3 = pack2(fast_exp2(sacc[is][r0+6]), fast_exp2(sacc[is][r0+7]));
        plane32_swap(W0, W2);
        plane32_swap(W1, W3);
        union { uint4v u; bf16x8 v; } cvt;
        cvt.u = (uint4v){ W0, W1, W2, W3 };
        pf[is*2 + hs] = cvt.v;
      }
    }

    // ---- PV: out[d 0..63][j] += V (A) x P (B); step kp covers i = kp*16..+15
    #pragma unroll
    for (int kp = 0; kp < 4; ++kp){
      #pragma unroll
      for (int ds = 0; ds < 2; ++ds){
        const int row = ds*32 + l31;
        const int g = (2*kp + lh) ^ (l31 & 7);
        bf16x8 vf = *(const bf16x8*)((const char*)&Vbuf[cur][0] + (size_t)row*128 + g*16);
        oacc[ds] = mfma32_bf16(vf, pf[kp], oacc[ds]);
      }
    }

    __syncthreads();   // vmcnt(0): prefetched tile t+1 landed; barrier for dbuf WAR
    cur ^= 1;
  }

  // epilogue: oacc[ds] reg r -> d = ds*32 + (r&3) + 8*(r>>2) + 4*lh, j = jw + l31
  #pragma unroll
  for (int ds = 0; ds < 2; ++ds){
    #pragma unroll
    for (int rq = 0; rq < 4; ++rq){
      const int d0 = ds*32 + 8*rq + 4*lh;
      ushort4v o = { f2bf(oacc[ds][4*rq+0]), f2bf(oacc[ds][4*rq+1]),
                     f2bf(oacc[ds][4*rq+2]), f2bf(oacc[ds][4*rq+3]) };
      *(ushort4v*)(AOt + ((size_t)b*Ld + jw + l31)*Sd + h*64 + d0) = o;
    }
  }
}

// ---------------- launch ----------------

extern "C" void kernel_launch(void* const* d_in, const int* in_sizes, int n_in,
                              void* d_out, int out_size, void* d_ws, size_t ws_size,
                              hipStream_t stream)
{
  const float* x  = (const float*)d_in[0];
  const float* Wk = (const float*)d_in[1];
  const float* bk = (const float*)d_in[2];
  const float* Wq = (const float*)d_in[3];
  const float* bq = (const float*)d_in[4];
  const float* Wp = (const float*)d_in[5];
  const float* bp = (const float*)d_in[6];
  float* out = (float*)d_out;

  char* ws = (char*)d_ws;
  const size_t SZ_BLS = (size_t)Bd * Ld * Sd * 2;   // 16 MB
  unsigned short* Xt   = (unsigned short*)(ws);
  unsigned short* Kt   = (unsigned short*)(ws + SZ_BLS);
  unsigned short* Qt   = (unsigned short*)(ws + 2*SZ_BLS);
  unsigned short* AOt  = (unsigned short*)(ws + 3*SZ_BLS);
  unsigned short* Wkbf = (unsigned short*)(ws + 4*SZ_BLS);
  unsigned short* Wqbf = (unsigned short*)(ws + 4*SZ_BLS + (size_t)2097152);
  unsigned short* Wpbf = (unsigned short*)(ws + 4*SZ_BLS + (size_t)2*2097152);
  float* invZ          = (float*)(ws + 4*SZ_BLS + (size_t)3*2097152);
  unsigned short* Vp   = Xt;  // alias: Xt is dead after the Q conv

  const float ck = (2.0f / (float)Ld) * 1.44269504088896f;

  wcast_kernel<<<1024, 256, 0, stream>>>(Wk, Wq, Wp, Wkbf, Wqbf, Wpbf, ck);
  transpose_cast<<<dim3(Ld/32, Sd/32, Bd), dim3(32, 8), 0, stream>>>(x, Xt);

  dim3 cg(Ld/128, Sd/128, Bd);
  conv_gemm<0><<<cg, 256, 0, stream>>>(Wkbf, Xt, bk, ck,   Kt, nullptr);
  conv_gemm<0><<<cg, 256, 0, stream>>>(Wqbf, Xt, bq, 1.0f, Qt, nullptr);

  stats_kernel<<<dim3(Ld/64, Bd*Hd), 256, 0, stream>>>(Kt, Qt, invZ);
  vprime_kernel<<<(Bd*(size_t)Sd*Ld/4)/256, 256, 0, stream>>>(x, invZ, Vp);
  attn_pv_kernel<<<dim3((Ld/128)*(Bd*Hd)), 256, 0, stream>>>(Kt, Qt, Vp, AOt);

  conv_gemm<1><<<cg, 256, 0, stream>>>(Wpbf, AOt, bp, 1.0f, nullptr, out);
}

// Round 5
// 235.565 us; speedup vs baseline: 1.7928x; 1.0946x over previous
//
#include <hip/hip_runtime.h>
#include <hip/hip_bf16.h>
#include <cstdint>
#include <cstddef>

#ifndef __has_builtin
#define __has_builtin(x) 0
#endif

#define DEVI __device__ __forceinline__

typedef __attribute__((ext_vector_type(8))) __bf16 bf16x8;
typedef __attribute__((ext_vector_type(4))) float float4v;
typedef __attribute__((ext_vector_type(16))) float float16v;
typedef __attribute__((ext_vector_type(4))) unsigned short ushort4v;
typedef __attribute__((ext_vector_type(4))) unsigned int uint4v;

constexpr int Bd = 4, Sd = 1024, Ld = 2048, Hd = 16, Dd = 64;

DEVI unsigned short f2bf(float x){
  union { float f; unsigned u; } v; v.f = x;
  unsigned r = v.u + 0x7fffu + ((v.u >> 16) & 1u);
  return (unsigned short)(r >> 16);
}

// RNE-pack two f32 -> one u32 of 2 bf16 (lo | hi<<16). Bitwise == f2bf pair.
DEVI unsigned pack2(float lo, float hi){
  union { float f; unsigned u; } a, b; a.f = lo; b.f = hi;
  unsigned ra = a.u + 0x7fffu + ((a.u >> 16) & 1u);
  unsigned rb = b.u + 0x7fffu + ((b.u >> 16) & 1u);
#if __has_builtin(__builtin_amdgcn_perm)
  return __builtin_amdgcn_perm(rb, ra, 0x07060302u);  // D = [rb.hi16 | ra.hi16]
#else
  return (ra >> 16) | (rb & 0xffff0000u);
#endif
}

DEVI float fast_exp2(float x){
#if __has_builtin(__builtin_amdgcn_exp2f)
  return __builtin_amdgcn_exp2f(x);
#else
  return exp2f(x);
#endif
}

// v_permlane32_swap_b32 D,S: new_D=[D.lo|S.lo], new_S=[D.hi|S.hi] (lane halves).
DEVI void plane32_swap(unsigned &a, unsigned &b){
  asm("v_permlane32_swap_b32 %0, %1" : "+v"(a), "+v"(b));
}

DEVI void gload_lds16(const void* g, void* lds){
  __builtin_amdgcn_global_load_lds(
      (const __attribute__((address_space(1))) void*)g,
      (__attribute__((address_space(3))) void*)lds,
      16, 0, 0);
}

DEVI float4v mfma_bf16(bf16x8 a, bf16x8 b, float4v c){
  return __builtin_amdgcn_mfma_f32_16x16x32_bf16(a, b, c, 0, 0, 0);
}

DEVI float16v mfma32_bf16(bf16x8 a, bf16x8 b, float16v c){
  return __builtin_amdgcn_mfma_f32_32x32x16_bf16(a, b, c, 0, 0, 0);
}

// ---------------- prep kernels ----------------

__global__ void wcast_kernel(const float* __restrict__ Wk, const float* __restrict__ Wq,
                             const float* __restrict__ Wp,
                             unsigned short* __restrict__ Wkbf, unsigned short* __restrict__ Wqbf,
                             unsigned short* __restrict__ Wpbf, float ck){
  size_t i = ((size_t)blockIdx.x * 256 + threadIdx.x) * 4;
  float4v a = *(const float4v*)(Wk + i);
  float4v b = *(const float4v*)(Wq + i);
  float4v c = *(const float4v*)(Wp + i);
  ushort4v oa = { f2bf(a[0]*ck), f2bf(a[1]*ck), f2bf(a[2]*ck), f2bf(a[3]*ck) };
  ushort4v ob = { f2bf(b[0]), f2bf(b[1]), f2bf(b[2]), f2bf(b[3]) };
  ushort4v oc = { f2bf(c[0]), f2bf(c[1]), f2bf(c[2]), f2bf(c[3]) };
  *(ushort4v*)(Wkbf + i) = oa;
  *(ushort4v*)(Wqbf + i) = ob;
  *(ushort4v*)(Wpbf + i) = oc;
}

// x (B,S,L) f32 -> Xt (B,L,S) bf16
__global__ void transpose_cast(const float* __restrict__ x, unsigned short* __restrict__ Xt){
  __shared__ float tile[32][33];
  const int b = blockIdx.z;
  const int l0 = blockIdx.x * 32;
  const int s0 = blockIdx.y * 32;
  const int tx = threadIdx.x, ty = threadIdx.y;  // 32 x 8
  #pragma unroll
  for (int r = 0; r < 32; r += 8)
    tile[ty + r][tx] = x[((size_t)b*Sd + s0 + ty + r)*Ld + l0 + tx];
  __syncthreads();
  #pragma unroll
  for (int r = 0; r < 32; r += 8)
    Xt[((size_t)b*Ld + l0 + ty + r)*Sd + s0 + tx] = f2bf(tile[tx][ty + r]);
}

// Vp[b][c][l] = bf16( x[b][c][l] * invZ[(b*16 + c/64)][l] )
__global__ void vprime_kernel(const float* __restrict__ x, const float* __restrict__ invZ,
                              unsigned short* __restrict__ Vp){
  size_t idx = ((size_t)blockIdx.x * 256 + threadIdx.x) * 4;
  const int l = (int)(idx & (Ld - 1));
  const int c = (int)((idx >> 11) & (Sd - 1));
  const int b = (int)(idx >> 21);
  const int h = c >> 6;
  float4v xv = *(const float4v*)(x + idx);
  float4v zv = *(const float4v*)(invZ + ((size_t)(b*Hd + h) * Ld + l));
  ushort4v o = { f2bf(xv[0]*zv[0]), f2bf(xv[1]*zv[1]), f2bf(xv[2]*zv[2]), f2bf(xv[3]*zv[3]) };
  *(ushort4v*)(Vp + idx) = o;
}

// ---------------- conv1x1 GEMM (128x128 tile, BK=32, dbuf, global_load_lds) ----------------
template<int OUT_MODE>
__global__ __launch_bounds__(256, 2)
void conv_gemm(const unsigned short* __restrict__ A,
               const unsigned short* __restrict__ Bt,
               const float* __restrict__ bias, float bscale,
               unsigned short* __restrict__ outT,
               float* __restrict__ outF)
{
  constexpr int BK = 32;
  constexpr int NKSTEP = Sd / BK;  // 32
  __shared__ __attribute__((aligned(16))) unsigned short Abuf[2][128*BK];
  __shared__ __attribute__((aligned(16))) unsigned short Bbuf[2][128*BK];

  const int b  = blockIdx.z;
  const int n0 = blockIdx.x * 128;
  const int m0 = blockIdx.y * 128;
  const int tid = threadIdx.x;
  const int w = tid >> 6, lane = tid & 63, lr = lane & 15, lg = lane >> 4;
  const int wm = (w >> 1) * 64, wn = (w & 1) * 64;

  const unsigned short* Abase = A + (size_t)m0 * Sd;
  const unsigned short* Bbase = Bt + ((size_t)b * Ld + n0) * Sd;

  auto stage = [&](int bf, int kt){
    #pragma unroll
    for (int p = 0; p < 2; ++p){
      int slot = p*256 + tid;
      int row = slot >> 2, c = slot & 3;
      int csrc = c ^ ((row >> 1) & 3);
      gload_lds16(Abase + (size_t)row * Sd + kt*BK + csrc*8,
                  (void*)(&Abuf[bf][(size_t)(p*256 + w*64) * 8]));
    }
    #pragma unroll
    for (int p = 0; p < 2; ++p){
      int slot = p*256 + tid;
      int row = slot >> 2, c = slot & 3;
      int csrc = c ^ ((row >> 1) & 3);
      gload_lds16(Bbase + (size_t)row * Sd + kt*BK + csrc*8,
                  (void*)(&Bbuf[bf][(size_t)(p*256 + w*64) * 8]));
    }
  };

  const int gsw = lg ^ ((lr >> 1) & 3);

  float4v acc[4][4];
  #pragma unroll
  for (int i = 0; i < 4; ++i)
    #pragma unroll
    for (int j = 0; j < 4; ++j)
      acc[i][j] = (float4v){0.f, 0.f, 0.f, 0.f};

  stage(0, 0);
  __syncthreads();
  int cur = 0;
  for (int kt = 0; kt < NKSTEP; ++kt){
    if (kt + 1 < NKSTEP) stage(cur ^ 1, kt + 1);
    bf16x8 af[4], bfv[4];
    #pragma unroll
    for (int i = 0; i < 4; ++i){
      int row = wm + i*16 + lr;
      af[i] = *(const bf16x8*)((const char*)&Abuf[cur][0] + (size_t)row*64 + gsw*16);
    }
    #pragma unroll
    for (int j = 0; j < 4; ++j){
      int row = wn + j*16 + lr;
      bfv[j] = *(const bf16x8*)((const char*)&Bbuf[cur][0] + (size_t)row*64 + gsw*16);
    }
    #pragma unroll
    for (int i = 0; i < 4; ++i)
      #pragma unroll
      for (int j = 0; j < 4; ++j)
        acc[i][j] = mfma_bf16(af[i], bfv[j], acc[i][j]);
    __syncthreads();
    cur ^= 1;
  }

  #pragma unroll
  for (int i = 0; i < 4; ++i){
    const int mb = m0 + wm + i*16 + lg*4;
    float4v bv = *(const float4v*)(bias + mb);
    #pragma unroll
    for (int j = 0; j < 4; ++j){
      const int n = n0 + wn + j*16 + lr;
      float4v v = acc[i][j];
      float o0 = v[0] + bscale*bv[0];
      float o1 = v[1] + bscale*bv[1];
      float o2 = v[2] + bscale*bv[2];
      float o3 = v[3] + bscale*bv[3];
      if (OUT_MODE == 0){
        ushort4v o = { f2bf(o0), f2bf(o1), f2bf(o2), f2bf(o3) };
        *(ushort4v*)(outT + ((size_t)b*Ld + n)*Sd + mb) = o;
      } else {
        outF[((size_t)b*Sd + mb + 0)*Ld + n] = o0;
        outF[((size_t)b*Sd + mb + 1)*Ld + n] = o1;
        outF[((size_t)b*Sd + mb + 2)*Ld + n] = o2;
        outF[((size_t)b*Sd + mb + 3)*Ld + n] = o3;
      }
    }
  }
}

// ---------------- stats v2: invZ[bh][i] = 1 / sum_j 2^(K'^T Q) ----------------
// 32x32 MFMA; K-frags in regs (block owns i-range 128); Q streamed via dbuf LDS;
// per-lane column sum (no cross-lane work in the loop); XCD-aware block remap.
__global__ __launch_bounds__(256, 4)
void stats_kernel(const unsigned short* __restrict__ Kt,
                  const unsigned short* __restrict__ Qt,
                  float* __restrict__ invZ)
{
  __shared__ __attribute__((aligned(16))) unsigned short Qbuf[2][64*64];  // 16 KB

  const int m = blockIdx.x;
  const int xcd = m & 7, slot = m >> 3;        // 8 XCDs, 128 slots each
  const int bh = xcd * 8 + (slot >> 4);        // 8 bh per XCD
  const int ib = slot & 15;
  const int b = bh >> 4, h = bh & 15;
  const int i0 = ib * 128;

  const int tid = threadIdx.x, w = tid >> 6, lane = tid & 63;
  const int l31 = lane & 31, lh = lane >> 5;
  const int iw = i0 + w * 32;

  // K fragments (loop-invariant): B-operand, col i = iw+l31, k = d = ks*16+lh*8..+8
  bf16x8 kb[4];
  #pragma unroll
  for (int ks = 0; ks < 4; ++ks)
    kb[ks] = *(const bf16x8*)(Kt + ((size_t)b*Ld + iw + l31)*Sd + h*64 + ks*16 + lh*8);

  const size_t qbase = (size_t)b*Ld*Sd + (size_t)h*64;
  auto stage = [&](int bf, int jt){
    const int j0 = jt * 64;
    #pragma unroll
    for (int p = 0; p < 2; ++p){
      const int slot2 = p*256 + tid;
      const int row = slot2 >> 3;
      const int gsrc = (slot2 & 7) ^ (row & 7);
      gload_lds16(Qt + qbase + (size_t)(j0 + row)*Sd + gsrc*8,
                  (void*)(&Qbuf[bf][(size_t)slot2 * 8]));
    }
  };

  float z = 0.f;
  stage(0, 0);
  __syncthreads();
  int cur = 0;
  for (int jt = 0; jt < 32; ++jt){
    if (jt + 1 < 32) stage(cur ^ 1, jt + 1);
    #pragma unroll
    for (int js = 0; js < 2; ++js){
      float16v sacc;
      #pragma unroll
      for (int r = 0; r < 16; ++r) sacc[r] = 0.f;
      #pragma unroll
      for (int ks = 0; ks < 4; ++ks){
        const int row = js*32 + l31;
        const int g = (2*ks + lh) ^ (l31 & 7);
        bf16x8 qf = *(const bf16x8*)((const char*)&Qbuf[cur][0] + (size_t)row*128 + g*16);
        sacc = mfma32_bf16(qf, kb[ks], sacc);   // D[row=j][col=i=l31]
      }
      #pragma unroll
      for (int r = 0; r < 16; ++r) z += fast_exp2(sacc[r]);
    }
    __syncthreads();
    cur ^= 1;
  }

  z += __shfl_xor(z, 32, 64);   // combine the two lh halves (disjoint j-subsets)
  if (lh == 0)
    invZ[(size_t)bh * Ld + iw + l31] = 1.0f / z;
}

// ---------------- PV pass v4: 32x32 MFMA, in-register P (RNE pack + permlane), dbuf ----
// AOt[b][j][c] = sum_i Vp[c][i] * 2^(s[i,j])
__global__ __launch_bounds__(256, 4)
void attn_pv_kernel(const unsigned short* __restrict__ Kt,
                    const unsigned short* __restrict__ Qt,
                    const unsigned short* __restrict__ Vp,
                    unsigned short* __restrict__ AOt)
{
  __shared__ __attribute__((aligned(16))) unsigned short Kbuf[2][64*64];  // 16 KB
  __shared__ __attribute__((aligned(16))) unsigned short Vbuf[2][64*64];  // 16 KB

  // XCD-aware remap: all 16 j-blocks of one bh on one XCD (K/V L2 reuse).
  const int m = blockIdx.x;
  const int xcd = m & 7, slot = m >> 3;        // 8 XCDs, 128 slots each
  const int bh = xcd * 8 + (slot >> 4);        // 8 bh per XCD
  const int jb = slot & 15;
  const int b = bh >> 4, h = bh & 15;
  const int j0 = jb * 128;

  const int tid = threadIdx.x, w = tid >> 6, lane = tid & 63;
  const int l31 = lane & 31, lh = lane >> 5;
  const int jw = j0 + w * 32;

  // Q fragments (loop-invariant): B-operand, col j = jw+l31, k-elems d = ks*16+lh*8..+8
  bf16x8 qb[4];
  #pragma unroll
  for (int ks = 0; ks < 4; ++ks)
    qb[ks] = *(const bf16x8*)(Qt + ((size_t)b*Ld + jw + l31)*Sd + h*64 + ks*16 + lh*8);

  float16v oacc[2];
  #pragma unroll
  for (int ds = 0; ds < 2; ++ds)
    #pragma unroll
    for (int r = 0; r < 16; ++r) oacc[ds][r] = 0.f;

  const size_t kbase = (size_t)b*Ld*Sd + (size_t)h*64;
  const size_t vbase = ((size_t)b*Sd + h*64)*Ld;

  // stage: K tile (64 i-rows x 64 d) and V tile (64 d-rows x 64 i), 8 KB each.
  // LDS linear (granule slot = row*8+g); source granule XOR-swizzled: gsrc = g ^ (row&7).
  auto stage = [&](int bf, int it){
    const int i0 = it * 64;
    #pragma unroll
    for (int p = 0; p < 2; ++p){
      const int slot2 = p*256 + tid;
      const int row = slot2 >> 3;
      const int gsrc = (slot2 & 7) ^ (row & 7);
      gload_lds16(Kt + kbase + (size_t)(i0 + row)*Sd + gsrc*8,
                  (void*)(&Kbuf[bf][(size_t)slot2 * 8]));
      gload_lds16(Vp + vbase + (size_t)row*Ld + i0 + gsrc*8,
                  (void*)(&Vbuf[bf][(size_t)slot2 * 8]));
    }
  };

  stage(0, 0);
  __syncthreads();
  int cur = 0;
  for (int it = 0; it < 32; ++it){
    if (it + 1 < 32) stage(cur ^ 1, it + 1);   // prefetch overlaps compute below

    // ---- QK^T: S[i 0..63][j wave32] in two 32x32 accs (lane holds col j = l31)
    float16v sacc[2];
    #pragma unroll
    for (int is = 0; is < 2; ++is){
      #pragma unroll
      for (int r = 0; r < 16; ++r) sacc[is][r] = 0.f;
      #pragma unroll
      for (int ks = 0; ks < 4; ++ks){
        const int row = is*32 + l31;
        const int g = (2*ks + lh) ^ (l31 & 7);
        bf16x8 kf = *(const bf16x8*)((const char*)&Kbuf[cur][0] + (size_t)row*128 + g*16);
        sacc[is] = mfma32_bf16(kf, qb[ks], sacc[is]);
      }
    }

    // ---- exp2 + RNE pack + permlane32_swap -> in-register PV B-frags.
    bf16x8 pf[4];
    #pragma unroll
    for (int is = 0; is < 2; ++is){
      #pragma unroll
      for (int hs = 0; hs < 2; ++hs){
        const int r0 = 8*hs;
        unsigned W0 = pack2(fast_exp2(sacc[is][r0+0]), fast_exp2(sacc[is][r0+1]));
        unsigned W1 = pack2(fast_exp2(sacc[is][r0+2]), fast_exp2(sacc[is][r0+3]));
        unsigned W2 = pack2(fast_exp2(sacc[is][r0+4]), fast_exp2(sacc[is][r0+5]));
        unsigned W3 = pack2(fast_exp2(sacc[is][r0+6]), fast_exp2(sacc[is][r0+7]));
        plane32_swap(W0, W2);
        plane32_swap(W1, W3);
        union { uint4v u; bf16x8 v; } cvt;
        cvt.u = (uint4v){ W0, W1, W2, W3 };
        pf[is*2 + hs] = cvt.v;
      }
    }

    // ---- PV: out[d 0..63][j] += V (A) x P (B); step kp covers i = kp*16..+15
    #pragma unroll
    for (int kp = 0; kp < 4; ++kp){
      #pragma unroll
      for (int ds = 0; ds < 2; ++ds){
        const int row = ds*32 + l31;
        const int g = (2*kp + lh) ^ (l31 & 7);
        bf16x8 vf = *(const bf16x8*)((const char*)&Vbuf[cur][0] + (size_t)row*128 + g*16);
        oacc[ds] = mfma32_bf16(vf, pf[kp], oacc[ds]);
      }
    }

    __syncthreads();   // vmcnt(0): prefetched tile t+1 landed; barrier for dbuf WAR
    cur ^= 1;
  }

  // epilogue: oacc[ds] reg r -> d = ds*32 + (r&3) + 8*(r>>2) + 4*lh, j = jw + l31
  #pragma unroll
  for (int ds = 0; ds < 2; ++ds){
    #pragma unroll
    for (int rq = 0; rq < 4; ++rq){
      const int d0 = ds*32 + 8*rq + 4*lh;
      ushort4v o = { f2bf(oacc[ds][4*rq+0]), f2bf(oacc[ds][4*rq+1]),
                     f2bf(oacc[ds][4*rq+2]), f2bf(oacc[ds][4*rq+3]) };
      *(ushort4v*)(AOt + ((size_t)b*Ld + jw + l31)*Sd + h*64 + d0) = o;
    }
  }
}

// ---------------- launch ----------------

extern "C" void kernel_launch(void* const* d_in, const int* in_sizes, int n_in,
                              void* d_out, int out_size, void* d_ws, size_t ws_size,
                              hipStream_t stream)
{
  const float* x  = (const float*)d_in[0];
  const float* Wk = (const float*)d_in[1];
  const float* bk = (const float*)d_in[2];
  const float* Wq = (const float*)d_in[3];
  const float* bq = (const float*)d_in[4];
  const float* Wp = (const float*)d_in[5];
  const float* bp = (const float*)d_in[6];
  float* out = (float*)d_out;

  char* ws = (char*)d_ws;
  const size_t SZ_BLS = (size_t)Bd * Ld * Sd * 2;   // 16 MB
  unsigned short* Xt   = (unsigned short*)(ws);
  unsigned short* Kt   = (unsigned short*)(ws + SZ_BLS);
  unsigned short* Qt   = (unsigned short*)(ws + 2*SZ_BLS);
  unsigned short* AOt  = (unsigned short*)(ws + 3*SZ_BLS);
  unsigned short* Wkbf = (unsigned short*)(ws + 4*SZ_BLS);
  unsigned short* Wqbf = (unsigned short*)(ws + 4*SZ_BLS + (size_t)2097152);
  unsigned short* Wpbf = (unsigned short*)(ws + 4*SZ_BLS + (size_t)2*2097152);
  float* invZ          = (float*)(ws + 4*SZ_BLS + (size_t)3*2097152);
  unsigned short* Vp   = Xt;  // alias: Xt is dead after the Q conv

  const float ck = (2.0f / (float)Ld) * 1.44269504088896f;

  wcast_kernel<<<1024, 256, 0, stream>>>(Wk, Wq, Wp, Wkbf, Wqbf, Wpbf, ck);
  transpose_cast<<<dim3(Ld/32, Sd/32, Bd), dim3(32, 8), 0, stream>>>(x, Xt);

  dim3 cg(Ld/128, Sd/128, Bd);
  conv_gemm<0><<<cg, 256, 0, stream>>>(Wkbf, Xt, bk, ck,   Kt, nullptr);
  conv_gemm<0><<<cg, 256, 0, stream>>>(Wqbf, Xt, bq, 1.0f, Qt, nullptr);

  stats_kernel<<<dim3((Ld/128)*(Bd*Hd)), 256, 0, stream>>>(Kt, Qt, invZ);
  vprime_kernel<<<(Bd*(size_t)Sd*Ld/4)/256, 256, 0, stream>>>(x, invZ, Vp);
  attn_pv_kernel<<<dim3((Ld/128)*(Bd*Hd)), 256, 0, stream>>>(Kt, Qt, Vp, AOt);

  conv_gemm<1><<<cg, 256, 0, stream>>>(Wpbf, AOt, bp, 1.0f, nullptr, out);
}

// Round 6
// 227.456 us; speedup vs baseline: 1.8567x; 1.0357x over previous
//
#include <hip/hip_runtime.h>
#include <hip/hip_bf16.h>
#include <cstdint>
#include <cstddef>

#ifndef __has_builtin
#define __has_builtin(x) 0
#endif

#define DEVI __device__ __forceinline__

typedef __attribute__((ext_vector_type(8))) __bf16 bf16x8;
typedef __attribute__((ext_vector_type(4))) float float4v;
typedef __attribute__((ext_vector_type(16))) float float16v;
typedef __attribute__((ext_vector_type(4))) unsigned short ushort4v;
typedef __attribute__((ext_vector_type(4))) unsigned int uint4v;

constexpr int Bd = 4, Sd = 1024, Ld = 2048, Hd = 16, Dd = 64;

DEVI unsigned short f2bf(float x){
  union { float f; unsigned u; } v; v.f = x;
  unsigned r = v.u + 0x7fffu + ((v.u >> 16) & 1u);
  return (unsigned short)(r >> 16);
}

// Half-up pack two f32 -> u32 of 2 bf16 (lo | hi<<16). 3 VALU ops.
// Differs from RNE only on exact-tie mantissas (1 ulp, ~2^-16 probability).
DEVI unsigned pack2(float lo, float hi){
  union { float f; unsigned u; } a, b; a.f = lo; b.f = hi;
  unsigned ra = a.u + 0x8000u;
  unsigned rb = b.u + 0x8000u;
#if __has_builtin(__builtin_amdgcn_perm)
  return __builtin_amdgcn_perm(rb, ra, 0x07060302u);  // D = [rb.hi16 | ra.hi16]
#else
  return (ra >> 16) | (rb & 0xffff0000u);
#endif
}

DEVI float fast_exp2(float x){
#if __has_builtin(__builtin_amdgcn_exp2f)
  return __builtin_amdgcn_exp2f(x);
#else
  return exp2f(x);
#endif
}

// v_permlane32_swap_b32 D,S: new_D=[D.lo|S.lo], new_S=[D.hi|S.hi] (lane halves).
DEVI void plane32_swap(unsigned &a, unsigned &b){
  asm("v_permlane32_swap_b32 %0, %1" : "+v"(a), "+v"(b));
}

DEVI void gload_lds16(const void* g, void* lds){
  __builtin_amdgcn_global_load_lds(
      (const __attribute__((address_space(1))) void*)g,
      (__attribute__((address_space(3))) void*)lds,
      16, 0, 0);
}

DEVI float4v mfma_bf16(bf16x8 a, bf16x8 b, float4v c){
  return __builtin_amdgcn_mfma_f32_16x16x32_bf16(a, b, c, 0, 0, 0);
}

DEVI float16v mfma32_bf16(bf16x8 a, bf16x8 b, float16v c){
  return __builtin_amdgcn_mfma_f32_32x32x16_bf16(a, b, c, 0, 0, 0);
}

// ---------------- prep kernels ----------------

__global__ void wcast_kernel(const float* __restrict__ Wk, const float* __restrict__ Wq,
                             const float* __restrict__ Wp,
                             unsigned short* __restrict__ Wkbf, unsigned short* __restrict__ Wqbf,
                             unsigned short* __restrict__ Wpbf, float ck){
  size_t i = ((size_t)blockIdx.x * 256 + threadIdx.x) * 4;
  float4v a = *(const float4v*)(Wk + i);
  float4v b = *(const float4v*)(Wq + i);
  float4v c = *(const float4v*)(Wp + i);
  ushort4v oa = { f2bf(a[0]*ck), f2bf(a[1]*ck), f2bf(a[2]*ck), f2bf(a[3]*ck) };
  ushort4v ob = { f2bf(b[0]), f2bf(b[1]), f2bf(b[2]), f2bf(b[3]) };
  ushort4v oc = { f2bf(c[0]), f2bf(c[1]), f2bf(c[2]), f2bf(c[3]) };
  *(ushort4v*)(Wkbf + i) = oa;
  *(ushort4v*)(Wqbf + i) = ob;
  *(ushort4v*)(Wpbf + i) = oc;
}

// x (B,S,L) f32 -> Xt (B,L,S) bf16
__global__ void transpose_cast(const float* __restrict__ x, unsigned short* __restrict__ Xt){
  __shared__ float tile[32][33];
  const int b = blockIdx.z;
  const int l0 = blockIdx.x * 32;
  const int s0 = blockIdx.y * 32;
  const int tx = threadIdx.x, ty = threadIdx.y;  // 32 x 8
  #pragma unroll
  for (int r = 0; r < 32; r += 8)
    tile[ty + r][tx] = x[((size_t)b*Sd + s0 + ty + r)*Ld + l0 + tx];
  __syncthreads();
  #pragma unroll
  for (int r = 0; r < 32; r += 8)
    Xt[((size_t)b*Ld + l0 + ty + r)*Sd + s0 + tx] = f2bf(tile[tx][ty + r]);
}

// Vp[b][c][l] = bf16( x[b][c][l] * invZ[(b*16 + c/64)][l] )
__global__ void vprime_kernel(const float* __restrict__ x, const float* __restrict__ invZ,
                              unsigned short* __restrict__ Vp){
  size_t idx = ((size_t)blockIdx.x * 256 + threadIdx.x) * 4;
  const int l = (int)(idx & (Ld - 1));
  const int c = (int)((idx >> 11) & (Sd - 1));
  const int b = (int)(idx >> 21);
  const int h = c >> 6;
  float4v xv = *(const float4v*)(x + idx);
  float4v zv = *(const float4v*)(invZ + ((size_t)(b*Hd + h) * Ld + l));
  ushort4v o = { f2bf(xv[0]*zv[0]), f2bf(xv[1]*zv[1]), f2bf(xv[2]*zv[2]), f2bf(xv[3]*zv[3]) };
  *(ushort4v*)(Vp + idx) = o;
}

// ---------------- conv1x1 GEMM (128x128 tile, BK=32, dbuf, global_load_lds) ----------------
template<int OUT_MODE>
__global__ __launch_bounds__(256, 2)
void conv_gemm(const unsigned short* __restrict__ A,
               const unsigned short* __restrict__ Bt,
               const float* __restrict__ bias, float bscale,
               unsigned short* __restrict__ outT,
               float* __restrict__ outF)
{
  constexpr int BK = 32;
  constexpr int NKSTEP = Sd / BK;  // 32
  __shared__ __attribute__((aligned(16))) unsigned short Abuf[2][128*BK];
  __shared__ __attribute__((aligned(16))) unsigned short Bbuf[2][128*BK];

  const int b  = blockIdx.z;
  const int n0 = blockIdx.x * 128;
  const int m0 = blockIdx.y * 128;
  const int tid = threadIdx.x;
  const int w = tid >> 6, lane = tid & 63, lr = lane & 15, lg = lane >> 4;
  const int wm = (w >> 1) * 64, wn = (w & 1) * 64;

  const unsigned short* Abase = A + (size_t)m0 * Sd;
  const unsigned short* Bbase = Bt + ((size_t)b * Ld + n0) * Sd;

  auto stage = [&](int bf, int kt){
    #pragma unroll
    for (int p = 0; p < 2; ++p){
      int slot = p*256 + tid;
      int row = slot >> 2, c = slot & 3;
      int csrc = c ^ ((row >> 1) & 3);
      gload_lds16(Abase + (size_t)row * Sd + kt*BK + csrc*8,
                  (void*)(&Abuf[bf][(size_t)(p*256 + w*64) * 8]));
    }
    #pragma unroll
    for (int p = 0; p < 2; ++p){
      int slot = p*256 + tid;
      int row = slot >> 2, c = slot & 3;
      int csrc = c ^ ((row >> 1) & 3);
      gload_lds16(Bbase + (size_t)row * Sd + kt*BK + csrc*8,
                  (void*)(&Bbuf[bf][(size_t)(p*256 + w*64) * 8]));
    }
  };

  const int gsw = lg ^ ((lr >> 1) & 3);

  float4v acc[4][4];
  #pragma unroll
  for (int i = 0; i < 4; ++i)
    #pragma unroll
    for (int j = 0; j < 4; ++j)
      acc[i][j] = (float4v){0.f, 0.f, 0.f, 0.f};

  stage(0, 0);
  __syncthreads();
  int cur = 0;
  for (int kt = 0; kt < NKSTEP; ++kt){
    if (kt + 1 < NKSTEP) stage(cur ^ 1, kt + 1);
    bf16x8 af[4], bfv[4];
    #pragma unroll
    for (int i = 0; i < 4; ++i){
      int row = wm + i*16 + lr;
      af[i] = *(const bf16x8*)((const char*)&Abuf[cur][0] + (size_t)row*64 + gsw*16);
    }
    #pragma unroll
    for (int j = 0; j < 4; ++j){
      int row = wn + j*16 + lr;
      bfv[j] = *(const bf16x8*)((const char*)&Bbuf[cur][0] + (size_t)row*64 + gsw*16);
    }
    #pragma unroll
    for (int i = 0; i < 4; ++i)
      #pragma unroll
      for (int j = 0; j < 4; ++j)
        acc[i][j] = mfma_bf16(af[i], bfv[j], acc[i][j]);
    __syncthreads();
    cur ^= 1;
  }

  #pragma unroll
  for (int i = 0; i < 4; ++i){
    const int mb = m0 + wm + i*16 + lg*4;
    float4v bv = *(const float4v*)(bias + mb);
    #pragma unroll
    for (int j = 0; j < 4; ++j){
      const int n = n0 + wn + j*16 + lr;
      float4v v = acc[i][j];
      float o0 = v[0] + bscale*bv[0];
      float o1 = v[1] + bscale*bv[1];
      float o2 = v[2] + bscale*bv[2];
      float o3 = v[3] + bscale*bv[3];
      if (OUT_MODE == 0){
        ushort4v o = { f2bf(o0), f2bf(o1), f2bf(o2), f2bf(o3) };
        *(ushort4v*)(outT + ((size_t)b*Ld + n)*Sd + mb) = o;
      } else {
        outF[((size_t)b*Sd + mb + 0)*Ld + n] = o0;
        outF[((size_t)b*Sd + mb + 1)*Ld + n] = o1;
        outF[((size_t)b*Sd + mb + 2)*Ld + n] = o2;
        outF[((size_t)b*Sd + mb + 3)*Ld + n] = o3;
      }
    }
  }
}

// ---------------- stats v3: invZ[bh][i] = 1 / sum_j 2^(K'^T Q) ----------------
// i_wave = 64 (block i-range 256): 8 K-frags in regs feed 16 MFMA per Q-tile;
// Q streamed via dbuf LDS; per-lane column sums; XCD-aware block remap.
__global__ __launch_bounds__(256, 4)
void stats_kernel(const unsigned short* __restrict__ Kt,
                  const unsigned short* __restrict__ Qt,
                  float* __restrict__ invZ)
{
  __shared__ __attribute__((aligned(16))) unsigned short Qbuf[2][64*64];  // 16 KB

  const int m = blockIdx.x;                    // 512 blocks
  const int xcd = m & 7, slot = m >> 3;        // 64 slots per XCD
  const int bh = xcd * 8 + (slot >> 3);        // 8 bh per XCD
  const int ib = slot & 7;
  const int b = bh >> 4, h = bh & 15;
  const int i0 = ib * 256;

  const int tid = threadIdx.x, w = tid >> 6, lane = tid & 63;
  const int l31 = lane & 31, lh = lane >> 5;
  const int iw0 = i0 + w * 64;

  // K fragments (loop-invariant): B-operand, col i = iw0 + is*32 + l31
  bf16x8 kb[2][4];
  #pragma unroll
  for (int is = 0; is < 2; ++is)
    #pragma unroll
    for (int ks = 0; ks < 4; ++ks)
      kb[is][ks] = *(const bf16x8*)(Kt + ((size_t)b*Ld + iw0 + is*32 + l31)*Sd + h*64 + ks*16 + lh*8);

  const size_t qbase = (size_t)b*Ld*Sd + (size_t)h*64;
  auto stage = [&](int bf, int jt){
    const int j0 = jt * 64;
    #pragma unroll
    for (int p = 0; p < 2; ++p){
      const int slot2 = p*256 + tid;
      const int row = slot2 >> 3;
      const int gsrc = (slot2 & 7) ^ (row & 7);
      gload_lds16(Qt + qbase + (size_t)(j0 + row)*Sd + gsrc*8,
                  (void*)(&Qbuf[bf][(size_t)slot2 * 8]));
    }
  };

  float z[2] = {0.f, 0.f};
  stage(0, 0);
  __syncthreads();
  int cur = 0;
  for (int jt = 0; jt < 32; ++jt){
    if (jt + 1 < 32) stage(cur ^ 1, jt + 1);
    #pragma unroll
    for (int js = 0; js < 2; ++js){
      bf16x8 qf[4];
      #pragma unroll
      for (int ks = 0; ks < 4; ++ks){
        const int row = js*32 + l31;
        const int g = (2*ks + lh) ^ (l31 & 7);
        qf[ks] = *(const bf16x8*)((const char*)&Qbuf[cur][0] + (size_t)row*128 + g*16);
      }
      #pragma unroll
      for (int is = 0; is < 2; ++is){
        float16v sacc;
        #pragma unroll
        for (int r = 0; r < 16; ++r) sacc[r] = 0.f;
        __builtin_amdgcn_s_setprio(1);
        #pragma unroll
        for (int ks = 0; ks < 4; ++ks)
          sacc = mfma32_bf16(qf[ks], kb[is][ks], sacc);   // D[row=j][col=i]
        __builtin_amdgcn_s_setprio(0);
        #pragma unroll
        for (int r = 0; r < 16; ++r) z[is] += fast_exp2(sacc[r]);
      }
    }
    __syncthreads();
    cur ^= 1;
  }

  #pragma unroll
  for (int is = 0; is < 2; ++is){
    float zv = z[is] + __shfl_xor(z[is], 32, 64);  // two lh halves: disjoint j-subsets
    if (lh == 0)
      invZ[(size_t)bh * Ld + iw0 + is*32 + l31] = 1.0f / zv;
  }
}

// ---------------- PV pass v5: j_wave=64, K/V frags shared across 2 j-sets ----------------
// AOt[b][j][c] = sum_i Vp[c][i] * 2^(s[i,j])
__global__ __launch_bounds__(256, 2)
void attn_pv_kernel(const unsigned short* __restrict__ Kt,
                    const unsigned short* __restrict__ Qt,
                    const unsigned short* __restrict__ Vp,
                    unsigned short* __restrict__ AOt)
{
  __shared__ __attribute__((aligned(16))) unsigned short Kbuf[2][64*64];  // 16 KB
  __shared__ __attribute__((aligned(16))) unsigned short Vbuf[2][64*64];  // 16 KB

  const int m = blockIdx.x;                    // 512 blocks
  const int xcd = m & 7, slot = m >> 3;        // 64 slots per XCD
  const int bh = xcd * 8 + (slot >> 3);        // 8 bh per XCD
  const int jb = slot & 7;
  const int b = bh >> 4, h = bh & 15;
  const int j0 = jb * 256;

  const int tid = threadIdx.x, w = tid >> 6, lane = tid & 63;
  const int l31 = lane & 31, lh = lane >> 5;
  const int jw = j0 + w * 64;                  // wave owns 64 j-cols (2 sets of 32)

  // Q fragments (loop-invariant): B-operand, col j = jw + js*32 + l31
  bf16x8 qb[2][4];
  #pragma unroll
  for (int js = 0; js < 2; ++js)
    #pragma unroll
    for (int ks = 0; ks < 4; ++ks)
      qb[js][ks] = *(const bf16x8*)(Qt + ((size_t)b*Ld + jw + js*32 + l31)*Sd + h*64 + ks*16 + lh*8);

  float16v oacc[2][2];   // [ds][js]
  #pragma unroll
  for (int ds = 0; ds < 2; ++ds)
    #pragma unroll
    for (int js = 0; js < 2; ++js)
      #pragma unroll
      for (int r = 0; r < 16; ++r) oacc[ds][js][r] = 0.f;

  const size_t kbase = (size_t)b*Ld*Sd + (size_t)h*64;
  const size_t vbase = ((size_t)b*Sd + h*64)*Ld;

  // stage: K tile (64 i x 64 d) + V tile (64 d x 64 i), LDS linear, src XOR-swizzled.
  auto stage = [&](int bf, int it){
    const int i0 = it * 64;
    #pragma unroll
    for (int p = 0; p < 2; ++p){
      const int slot2 = p*256 + tid;
      const int row = slot2 >> 3;
      const int gsrc = (slot2 & 7) ^ (row & 7);
      gload_lds16(Kt + kbase + (size_t)(i0 + row)*Sd + gsrc*8,
                  (void*)(&Kbuf[bf][(size_t)slot2 * 8]));
      gload_lds16(Vp + vbase + (size_t)row*Ld + i0 + gsrc*8,
                  (void*)(&Vbuf[bf][(size_t)slot2 * 8]));
    }
  };

  stage(0, 0);
  __syncthreads();
  int cur = 0;
  for (int it = 0; it < 32; ++it){
    if (it + 1 < 32) stage(cur ^ 1, it + 1);   // prefetch overlaps compute below

    // ---- K and V fragments: 16 ds_read_b128, reused by BOTH j-sets (2x MFMA per read)
    bf16x8 kf[2][4], vf[2][4];
    #pragma unroll
    for (int is = 0; is < 2; ++is)
      #pragma unroll
      for (int ks = 0; ks < 4; ++ks){
        const int row = is*32 + l31;
        const int g = (2*ks + lh) ^ (l31 & 7);
        kf[is][ks] = *(const bf16x8*)((const char*)&Kbuf[cur][0] + (size_t)row*128 + g*16);
        vf[is][ks] = *(const bf16x8*)((const char*)&Vbuf[cur][0] + (size_t)row*128 + g*16);
      }

    #pragma unroll
    for (int js = 0; js < 2; ++js){
      // QK^T: S[i 0..63][j set js]
      float16v sacc[2];
      #pragma unroll
      for (int is = 0; is < 2; ++is){
        #pragma unroll
        for (int r = 0; r < 16; ++r) sacc[is][r] = 0.f;
      }
      __builtin_amdgcn_s_setprio(1);
      #pragma unroll
      for (int is = 0; is < 2; ++is)
        #pragma unroll
        for (int ks = 0; ks < 4; ++ks)
          sacc[is] = mfma32_bf16(kf[is][ks], qb[js][ks], sacc[is]);
      __builtin_amdgcn_s_setprio(0);

      // exp2 + half-up pack + permlane -> in-register PV B-frags
      bf16x8 pf[4];
      #pragma unroll
      for (int is = 0; is < 2; ++is){
        #pragma unroll
        for (int hs = 0; hs < 2; ++hs){
          const int r0 = 8*hs;
          unsigned W0 = pack2(fast_exp2(sacc[is][r0+0]), fast_exp2(sacc[is][r0+1]));
          unsigned W1 = pack2(fast_exp2(sacc[is][r0+2]), fast_exp2(sacc[is][r0+3]));
          unsigned W2 = pack2(fast_exp2(sacc[is][r0+4]), fast_exp2(sacc[is][r0+5]));
          unsigned W3 = pack2(fast_exp2(sacc[is][r0+6]), fast_exp2(sacc[is][r0+7]));
          plane32_swap(W0, W2);
          plane32_swap(W1, W3);
          union { uint4v u; bf16x8 v; } cvt;
          cvt.u = (uint4v){ W0, W1, W2, W3 };
          pf[is*2 + hs] = cvt.v;
        }
      }

      // PV: out[d 0..63][j set js] += V x P
      __builtin_amdgcn_s_setprio(1);
      #pragma unroll
      for (int kp = 0; kp < 4; ++kp)
        #pragma unroll
        for (int ds = 0; ds < 2; ++ds)
          oacc[ds][js] = mfma32_bf16(vf[ds][kp], pf[kp], oacc[ds][js]);
      __builtin_amdgcn_s_setprio(0);
    }

    __syncthreads();   // vmcnt(0): prefetched tile landed; barrier for dbuf WAR
    cur ^= 1;
  }

  // epilogue: oacc[ds][js] reg r -> d = ds*32 + (r&3)+8*(r>>2)+4*lh, j = jw + js*32 + l31
  #pragma unroll
  for (int ds = 0; ds < 2; ++ds)
    #pragma unroll
    for (int js = 0; js < 2; ++js)
      #pragma unroll
      for (int rq = 0; rq < 4; ++rq){
        const int d0 = ds*32 + 8*rq + 4*lh;
        ushort4v o = { f2bf(oacc[ds][js][4*rq+0]), f2bf(oacc[ds][js][4*rq+1]),
                       f2bf(oacc[ds][js][4*rq+2]), f2bf(oacc[ds][js][4*rq+3]) };
        *(ushort4v*)(AOt + ((size_t)b*Ld + jw + js*32 + l31)*Sd + h*64 + d0) = o;
      }
}

// ---------------- launch ----------------

extern "C" void kernel_launch(void* const* d_in, const int* in_sizes, int n_in,
                              void* d_out, int out_size, void* d_ws, size_t ws_size,
                              hipStream_t stream)
{
  const float* x  = (const float*)d_in[0];
  const float* Wk = (const float*)d_in[1];
  const float* bk = (const float*)d_in[2];
  const float* Wq = (const float*)d_in[3];
  const float* bq = (const float*)d_in[4];
  const float* Wp = (const float*)d_in[5];
  const float* bp = (const float*)d_in[6];
  float* out = (float*)d_out;

  char* ws = (char*)d_ws;
  const size_t SZ_BLS = (size_t)Bd * Ld * Sd * 2;   // 16 MB
  unsigned short* Xt   = (unsigned short*)(ws);
  unsigned short* Kt   = (unsigned short*)(ws + SZ_BLS);
  unsigned short* Qt   = (unsigned short*)(ws + 2*SZ_BLS);
  unsigned short* AOt  = (unsigned short*)(ws + 3*SZ_BLS);
  unsigned short* Wkbf = (unsigned short*)(ws + 4*SZ_BLS);
  unsigned short* Wqbf = (unsigned short*)(ws + 4*SZ_BLS + (size_t)2097152);
  unsigned short* Wpbf = (unsigned short*)(ws + 4*SZ_BLS + (size_t)2*2097152);
  float* invZ          = (float*)(ws + 4*SZ_BLS + (size_t)3*2097152);
  unsigned short* Vp   = Xt;  // alias: Xt is dead after the Q conv

  const float ck = (2.0f / (float)Ld) * 1.44269504088896f;

  wcast_kernel<<<1024, 256, 0, stream>>>(Wk, Wq, Wp, Wkbf, Wqbf, Wpbf, ck);
  transpose_cast<<<dim3(Ld/32, Sd/32, Bd), dim3(32, 8), 0, stream>>>(x, Xt);

  dim3 cg(Ld/128, Sd/128, Bd);
  conv_gemm<0><<<cg, 256, 0, stream>>>(Wkbf, Xt, bk, ck,   Kt, nullptr);
  conv_gemm<0><<<cg, 256, 0, stream>>>(Wqbf, Xt, bq, 1.0f, Qt, nullptr);

  stats_kernel<<<dim3((Ld/256)*(Bd*Hd)), 256, 0, stream>>>(Kt, Qt, invZ);
  vprime_kernel<<<(Bd*(size_t)Sd*Ld/4)/256, 256, 0, stream>>>(x, invZ, Vp);
  attn_pv_kernel<<<dim3((Ld/256)*(Bd*Hd)), 256, 0, stream>>>(Kt, Qt, Vp, AOt);

  conv_gemm<1><<<cg, 256, 0, stream>>>(Wpbf, AOt, bp, 1.0f, nullptr, out);
}